// Round 10
// baseline (326.629 us; speedup 1.0000x reference)
//
#include <hip/hip_runtime.h>
#include <hip/hip_bf16.h>

#define NNODE 50000
#define NEDGE 400000
#define NTOT  450000   // NEDGE + NNODE self-loops
#define FDIM  128
#define HEADS 8
#define SCANB ((NNODE + 255) / 256)   // 196 blocks
#define CSRC_PAD 256

typedef __bf16 bf16x8 __attribute__((ext_vector_type(8)));
typedef float  f32x4  __attribute__((ext_vector_type(4)));
typedef __hip_bfloat16 bf16;

// v_add with DPP cross-lane source: v + dpp(v). 0xB1=quad_perm[1,0,3,2](xor1),
// 0x4E=quad_perm[2,3,0,1](xor2), 0x141=row_half_mirror(xor4 after quad sums).
template<int CTRL>
static __device__ __forceinline__ float dpp_add(float v) {
  int x = __builtin_amdgcn_update_dpp(0, __float_as_int(v), CTRL, 0xf, 0xf, true);
  return v + __int_as_float(x);
}

// ---------------- CSR build ----------------

__global__ __launch_bounds__(256) void k_count(const int* __restrict__ ei, int* __restrict__ deg) {
  int t = blockIdx.x * 256 + threadIdx.x;
  if (t >= NTOT) return;
  int d = (t < NEDGE) ? ei[NEDGE + t] : (t - NEDGE);
  atomicAdd(&deg[d], 1);
}

__global__ __launch_bounds__(256) void k_scan1(const int* __restrict__ deg, int* __restrict__ offs,
                                               int* __restrict__ bsum) {
  __shared__ int buf[256];
  int i = blockIdx.x * 256 + threadIdx.x;
  int v = (i < NNODE) ? deg[i] : 0;
  buf[threadIdx.x] = v;
  __syncthreads();
  for (int off = 1; off < 256; off <<= 1) {
    int t = (threadIdx.x >= off) ? buf[threadIdx.x - off] : 0;
    __syncthreads();
    buf[threadIdx.x] += t;
    __syncthreads();
  }
  if (i < NNODE) offs[i + 1] = buf[threadIdx.x];
  if (threadIdx.x == 255) bsum[blockIdx.x] = buf[255];
  if (i == 0) offs[0] = 0;
}

__global__ __launch_bounds__(256) void k_scan2(int* __restrict__ bsum, int nb) {
  __shared__ int buf[256];
  int v = (threadIdx.x < nb) ? bsum[threadIdx.x] : 0;
  buf[threadIdx.x] = v;
  __syncthreads();
  for (int off = 1; off < 256; off <<= 1) {
    int t = (threadIdx.x >= off) ? buf[threadIdx.x - off] : 0;
    __syncthreads();
    buf[threadIdx.x] += t;
    __syncthreads();
  }
  if (threadIdx.x < nb) bsum[threadIdx.x] = buf[threadIdx.x] - v;
}

__global__ __launch_bounds__(256) void k_scan3(int* __restrict__ offs, const int* __restrict__ bsum) {
  int i = blockIdx.x * 256 + threadIdx.x;
  if (i < NNODE) offs[i + 1] += bsum[blockIdx.x];
}

__global__ __launch_bounds__(256) void k_fill(const int* __restrict__ ei, const int* __restrict__ offs,
                                              int* __restrict__ cur, int* __restrict__ csrc) {
  int t = blockIdx.x * 256 + threadIdx.x;
  if (t >= NTOT) return;
  int s, d;
  if (t < NEDGE) { s = ei[t]; d = ei[NEDGE + t]; }
  else { s = t - NEDGE; d = s; }
  int pos = offs[d] + atomicAdd(&cur[d], 1);
  csrc[pos] = s;
}

// ---------------- B pre-pack into MFMA fragment order ----------------

template<int K, int N>
__global__ __launch_bounds__(256) void k_pack(const float* __restrict__ Wl, const float* __restrict__ Wr,
                                              bf16* __restrict__ Bp) {
  constexpr int KS = K / 32;
  int t = blockIdx.x * 256 + threadIdx.x;
  if (t >= (N / 16) * KS * 64) return;
  int lane = t & 63;
  int ks = (t >> 6) % KS;
  int cb = t / (64 * KS);
  int col = cb * 16 + (lane & 15);
  int k0 = ks * 32 + (lane >> 4) * 8;
  const float* W = (col < N / 2) ? Wl : Wr;
  int c = (col < N / 2) ? col : col - N / 2;
  bf16* o = Bp + (size_t)t * 8;
#pragma unroll
  for (int j = 0; j < 8; ++j)
    o[j] = __float2bfloat16(W[(size_t)(k0 + j) * (N / 2) + c]);
}

// ---------------- MFMA dual GEMM (optional fused fp32->bf16 A-cast) ----------------

template<int K, int N, bool CVT>
__global__ __launch_bounds__(256) void k_mfma(const void* __restrict__ Aptr,
                                              const bf16* __restrict__ Bp,
                                              bf16* __restrict__ xl, bf16* __restrict__ xr,
                                              int n) {
  constexpr int KS = K / 32;
  const int lane = threadIdx.x & 63;
  const int wave = threadIdx.x >> 6;
  const int rb = blockIdx.x * 32;
  const int cb0 = blockIdx.y * 16 + wave * 4;
  const int r16 = lane & 15, kg = lane >> 4;

  bf16x8 a[2][KS];
#pragma unroll
  for (int mf = 0; mf < 2; ++mf) {
    int row = rb + 16 * mf + r16;
    if (row >= n) row = n - 1;
    if constexpr (CVT) {
      const float* pa = (const float*)Aptr + (size_t)row * K + kg * 8;
#pragma unroll
      for (int ks = 0; ks < KS; ++ks) {
        float4 f0 = *(const float4*)(pa + ks * 32);
        float4 f1 = *(const float4*)(pa + ks * 32 + 4);
        bf16x8 v;
        v[0] = __float2bfloat16(f0.x); v[1] = __float2bfloat16(f0.y);
        v[2] = __float2bfloat16(f0.z); v[3] = __float2bfloat16(f0.w);
        v[4] = __float2bfloat16(f1.x); v[5] = __float2bfloat16(f1.y);
        v[6] = __float2bfloat16(f1.z); v[7] = __float2bfloat16(f1.w);
        a[mf][ks] = v;
      }
    } else {
      const bf16* pa = (const bf16*)Aptr + (size_t)row * K + kg * 8;
#pragma unroll
      for (int ks = 0; ks < KS; ++ks)
        a[mf][ks] = *(const bf16x8*)(pa + ks * 32);
    }
  }

#pragma unroll
  for (int nf = 0; nf < 4; ++nf) {
    int cb = cb0 + nf;
    f32x4 acc0 = {0.f, 0.f, 0.f, 0.f}, acc1 = {0.f, 0.f, 0.f, 0.f};
    const bf16* pb = Bp + (size_t)cb * KS * 512 + lane * 8;
#pragma unroll
    for (int ks = 0; ks < KS; ++ks) {
      bf16x8 b = *(const bf16x8*)(pb + ks * 512);
      acc0 = __builtin_amdgcn_mfma_f32_16x16x32_bf16(a[0][ks], b, acc0, 0, 0, 0);
      acc1 = __builtin_amdgcn_mfma_f32_16x16x32_bf16(a[1][ks], b, acc1, 0, 0, 0);
    }
    int col = cb * 16 + r16;
    bf16* OUT; int c;
    if (col < N / 2) { OUT = xl; c = col; } else { OUT = xr; c = col - N / 2; }
#pragma unroll
    for (int reg = 0; reg < 4; ++reg) {
      int row0 = rb + kg * 4 + reg;
      if (row0 < n) OUT[(size_t)row0 * (N / 2) + c] = __float2bfloat16(acc0[reg]);
      int row1 = rb + 16 + kg * 4 + reg;
      if (row1 < n) OUT[(size_t)row1 * (N / 2) + c] = __float2bfloat16(acc1[reg]);
    }
  }
}

// ---------------- residual (fp32 vector; small) ----------------

__global__ __launch_bounds__(256) void k_residual(const float* __restrict__ X,
                                                  const float* __restrict__ W,
                                                  const float* __restrict__ b,
                                                  float* __restrict__ out, int n) {
  __shared__ float xs[8 * 128];
  int row0 = blockIdx.x * 8;
  for (int t = threadIdx.x; t < 8 * 128; t += 256) {
    int r = t >> 7;
    xs[t] = (row0 + r < n) ? X[(size_t)(row0 + r) * 128 + (t & 127)] : 0.f;
  }
  __syncthreads();
  int r = threadIdx.x >> 5, c = threadIdx.x & 31;
  float acc = 0.f;
  for (int k = 0; k < 128; ++k) acc += xs[r * 128 + k] * W[k * 32 + c];
  if (row0 + r < n) out[(size_t)(row0 + r) * 32 + c] = acc + b[c];
}

// ---------------- fused GATv2 layer (edge-split, all state in ext_vector regs) ----------------
// Block = W waves = ONE node; wave w handles edges beg+w, beg+w+W, ...
// Lane l: head l>>3, channels (l&7)*VEC + [0..VEC). Rows loaded as NW=VEC/2 u32 words.
// bf16->f32: lo = asfloat(w<<16), hi = asfloat(w & 0xffff0000).
// lrelu(t)*a = (0.6a)t + (0.4a)|t|; att prescaled by log2(e) so wgt = v_exp_f32(s).
// Max-free softmax (validated R6-R9). DPP score reduce. csrc is PADDED by CSRC_PAD
// zeroed ints -> unclamped 2-iteration-ahead index prefetch (no cmp/cndmask in loop).
// ALL per-lane state is ext_vector (register-allocated) - no local arrays (R9: float[]
// through lambda pointer defeated SROA -> scratch/AGPR traffic, ~4x VALU inflation).

template<int D, int VEC, int W, bool L1>
__global__ __launch_bounds__(64 * W, 3) void k_gat(const bf16* __restrict__ xl,
                                                   const bf16* __restrict__ xr,
                                                   const float* __restrict__ att,
                                                   const int* __restrict__ csrc,
                                                   const int* __restrict__ offs,
                                                   const float* __restrict__ bias,
                                                   const float* __restrict__ resid,
                                                   bf16* __restrict__ out1,
                                                   float* __restrict__ out2) {
  constexpr int CH = D / 8;
  constexpr int NW = VEC / 2;
  constexpr unsigned ROWB = D * 2;
  typedef unsigned int uivec __attribute__((ext_vector_type(NW)));
  typedef float fvec __attribute__((ext_vector_type(VEC)));
  __shared__ float sden[W - 1][64];
  __shared__ float sacc[W - 1][64][VEC + 1];
  const int w    = threadIdx.x >> 6;
  const int lane = threadIdx.x & 63;
  const int node = blockIdx.x;
  const int beg = offs[node], end = offs[node + 1];

  const unsigned loff = (unsigned)(lane * VEC) * 2u;
  const char* xlp = (const char*)xl + loff;

  auto cvt = [](uivec Wd) -> fvec {
    fvec r;
#pragma unroll
    for (int p = 0; p < NW; ++p) {
      r[2 * p]     = __uint_as_float(Wd[p] << 16);
      r[2 * p + 1] = __uint_as_float(Wd[p] & 0xffff0000u);
    }
    return r;
  };

  // per-lane constants: prescaled att halves + xr slice (all ext_vector regs)
  fvec a6, a4, xrv;
  {
    const float* pa = att + lane * VEC;
    uivec rw = *(const uivec*)((const char*)xr + (size_t)node * ROWB + loff);
    xrv = cvt(rw);
#pragma unroll
    for (int j = 0; j < VEC; ++j) {
      float a = pa[j] * 1.44269504f;   // fold exp->exp2
      a6[j] = 0.6f * a;
      a4[j] = 0.4f * a;
    }
  }

  float den = 0.f;
  fvec acc;
#pragma unroll
  for (int j = 0; j < VEC; ++j) acc[j] = 0.f;

  int i = beg + w;
  if (i < end) {
    // indices prefetched 2 unroll-iterations ahead (padded csrc: unclamped, safe)
    int c0 = csrc[i];
    int c1 = csrc[i + W];
    int c2 = csrc[i + 2 * W];
    int c3 = csrc[i + 3 * W];
    uivec A0 = *(const uivec*)(xlp + (unsigned)c0 * ROWB);
    uivec A1 = *(const uivec*)(xlp + (unsigned)c1 * ROWB);
    for (; i + W < end; i += 2 * W) {
      uivec B0 = *(const uivec*)(xlp + (unsigned)c2 * ROWB);
      uivec B1 = *(const uivec*)(xlp + (unsigned)c3 * ROWB);
      c2 = csrc[i + 4 * W];
      c3 = csrc[i + 5 * W];

      fvec av0 = cvt(A0);
      fvec av1 = cvt(A1);
      fvec t0 = av0 + xrv;
      fvec t1 = av1 + xrv;
      float s0a = 0.f, s0b = 0.f, s1a = 0.f, s1b = 0.f;
#pragma unroll
      for (int j = 0; j < VEC; ++j) {
        s0a = fmaf(a6[j], t0[j], s0a);
        s0b = fmaf(a4[j], fabsf(t0[j]), s0b);
        s1a = fmaf(a6[j], t1[j], s1a);
        s1b = fmaf(a4[j], fabsf(t1[j]), s1b);
      }
      float s0 = s0a + s0b, s1 = s1a + s1b;
      s0 = dpp_add<0xB1>(s0);   s1 = dpp_add<0xB1>(s1);
      s0 = dpp_add<0x4E>(s0);   s1 = dpp_add<0x4E>(s1);
      s0 = dpp_add<0x141>(s0);  s1 = dpp_add<0x141>(s1);
      float w0, w1;
      asm("v_exp_f32 %0, %1" : "=v"(w0) : "v"(s0));
      asm("v_exp_f32 %0, %1" : "=v"(w1) : "v"(s1));
      den += w0;
      den += w1;
#pragma unroll
      for (int j = 0; j < VEC; ++j) {
        acc[j] = fmaf(w0, av0[j], acc[j]);
        acc[j] = fmaf(w1, av1[j], acc[j]);
      }
      A0 = B0; A1 = B1;
    }
    if (i < end) {   // tail single edge
      fvec av0 = cvt(A0);
      fvec t0 = av0 + xrv;
      float s0a = 0.f, s0b = 0.f;
#pragma unroll
      for (int j = 0; j < VEC; ++j) {
        s0a = fmaf(a6[j], t0[j], s0a);
        s0b = fmaf(a4[j], fabsf(t0[j]), s0b);
      }
      float s0 = s0a + s0b;
      s0 = dpp_add<0xB1>(s0);
      s0 = dpp_add<0x4E>(s0);
      s0 = dpp_add<0x141>(s0);
      float w0;
      asm("v_exp_f32 %0, %1" : "=v"(w0) : "v"(s0));
      den += w0;
#pragma unroll
      for (int j = 0; j < VEC; ++j) acc[j] = fmaf(w0, av0[j], acc[j]);
    }
  }

  if (w > 0) {
    sden[w - 1][lane] = den;
#pragma unroll
    for (int j = 0; j < VEC; ++j) sacc[w - 1][lane][j] = acc[j];
  }
  __syncthreads();
  if (w == 0) {
#pragma unroll
    for (int ww = 0; ww < W - 1; ++ww) {
      den += sden[ww][lane];
#pragma unroll
      for (int j = 0; j < VEC; ++j) acc[j] += sacc[ww][lane][j];
    }
    const float inv = 1.f / den;
    fvec v;
#pragma unroll
    for (int j = 0; j < VEC; ++j) {
      float t = acc[j] * inv;
      t += __shfl_xor(t, 8);
      t += __shfl_xor(t, 16);
      t += __shfl_xor(t, 32);
      v[j] = t;
    }
    if (lane < 8) {
      int c0 = lane * VEC;
      if constexpr (L1) {
        bf16* o = out1 + (size_t)node * CH + c0;
#pragma unroll
        for (int j = 0; j < VEC; ++j) {
          float t = v[j] * 0.125f + bias[c0 + j];
          o[j] = __float2bfloat16(fmaxf(t, 0.f));
        }
      } else {
        float* o = out2 + (size_t)node * CH + c0;
        const float* rs = resid + (size_t)node * CH + c0;
#pragma unroll
        for (int j = 0; j < VEC; ++j)
          o[j] = v[j] * 0.125f + bias[c0 + j] + rs[j];
      }
    }
  }
}

// ---------------- launch ----------------

extern "C" void kernel_launch(void* const* d_in, const int* in_sizes, int n_in,
                              void* d_out, int out_size, void* d_ws, size_t ws_size,
                              hipStream_t stream) {
  const float* x      = (const float*)d_in[0];
  const int*   ei     = (const int*)d_in[1];
  const float* lin1_w = (const float*)d_in[3];
  const float* lin1_b = (const float*)d_in[4];
  const float* wl1    = (const float*)d_in[5];
  const float* wr1    = (const float*)d_in[6];
  const float* att1   = (const float*)d_in[7];
  const float* b1     = (const float*)d_in[8];
  const float* wl2    = (const float*)d_in[9];
  const float* wr2    = (const float*)d_in[10];
  const float* att2   = (const float*)d_in[11];
  const float* b2     = (const float*)d_in[12];
  float* out = (float*)d_out;

  char* p = (char*)d_ws;
  auto alloc = [&](size_t bytes) {
    char* r = p;
    p += (bytes + 255) & ~size_t(255);
    return r;
  };
  int*   offs  = (int*)alloc((NNODE + 1) * 4);
  int*   deg   = (int*)alloc(NNODE * 4);
  int*   cur   = (int*)alloc(NNODE * 4);
  int*   bsum  = (int*)alloc(SCANB * 4);
  int*   csrc  = (int*)alloc(((size_t)NTOT + CSRC_PAD) * 4);
  bf16*  xl    = (bf16*)alloc((size_t)NNODE * 512 * 2);
  bf16*  xr    = (bf16*)alloc((size_t)NNODE * 512 * 2);
  bf16*  h1    = (bf16*)alloc((size_t)NNODE * 64 * 2);
  bf16*  Bp1   = (bf16*)alloc((size_t)128 * 1024 * 2);
  bf16*  Bp2   = (bf16*)alloc((size_t)64 * 512 * 2);
  float* resid = (float*)alloc((size_t)NNODE * 32 * 4);

  (void)hipMemsetAsync(deg, 0, NNODE * 4, stream);
  (void)hipMemsetAsync(cur, 0, NNODE * 4, stream);
  (void)hipMemsetAsync(csrc + NTOT, 0, CSRC_PAD * 4, stream);

  // prep
  k_count<<<(NTOT + 255) / 256, 256, 0, stream>>>(ei, deg);
  k_scan1<<<SCANB, 256, 0, stream>>>(deg, offs, bsum);
  k_scan2<<<1, 256, 0, stream>>>(bsum, SCANB);
  k_scan3<<<SCANB, 256, 0, stream>>>(offs, bsum);
  k_fill<<<(NTOT + 255) / 256, 256, 0, stream>>>(ei, offs, cur, csrc);
  k_pack<128, 1024><<<64, 256, 0, stream>>>(wl1, wr1, Bp1);
  k_pack<64, 512><<<16, 256, 0, stream>>>(wl2, wr2, Bp2);
  k_residual<<<NNODE / 8, 256, 0, stream>>>(x, lin1_w, lin1_b, resid, NNODE);

  // layer 1 (A-cast fused into MFMA: reads fp32 x directly)
  k_mfma<128, 1024, true><<<dim3((NNODE + 31) / 32, 4), 256, 0, stream>>>(x, Bp1, xl, xr, NNODE);
  k_gat<512, 8, 4, true><<<NNODE, 256, 0, stream>>>(xl, xr, att1, csrc, offs, b1, nullptr, h1, nullptr);

  // layer 2
  k_mfma<64, 512, false><<<dim3((NNODE + 31) / 32, 2), 256, 0, stream>>>(h1, Bp2, xl, xr, NNODE);
  k_gat<256, 4, 4, false><<<NNODE, 256, 0, stream>>>(xl, xr, att2, csrc, offs, b2, resid, nullptr, out);
}

// Round 11
// 323.026 us; speedup vs baseline: 1.0112x; 1.0112x over previous
//
#include <hip/hip_runtime.h>
#include <hip/hip_bf16.h>

#define NNODE 50000
#define NEDGE 400000
#define NTOT  450000   // NEDGE + NNODE self-loops
#define FDIM  128
#define HEADS 8
#define SCANB ((NNODE + 255) / 256)   // 196 blocks

typedef __bf16 bf16x8 __attribute__((ext_vector_type(8)));
typedef float  f32x4  __attribute__((ext_vector_type(4)));
typedef __hip_bfloat16 bf16;

// v_add with DPP cross-lane source: v + dpp(v). 0xB1=quad_perm[1,0,3,2](xor1),
// 0x4E=quad_perm[2,3,0,1](xor2), 0x141=row_half_mirror(xor4 after quad sums).
template<int CTRL>
static __device__ __forceinline__ float dpp_add(float v) {
  int x = __builtin_amdgcn_update_dpp(0, __float_as_int(v), CTRL, 0xf, 0xf, true);
  return v + __int_as_float(x);
}

// ---------------- CSR build ----------------

__global__ __launch_bounds__(256) void k_count(const int* __restrict__ ei, int* __restrict__ deg) {
  int t = blockIdx.x * 256 + threadIdx.x;
  if (t >= NTOT) return;
  int d = (t < NEDGE) ? ei[NEDGE + t] : (t - NEDGE);
  atomicAdd(&deg[d], 1);
}

__global__ __launch_bounds__(256) void k_scan1(const int* __restrict__ deg, int* __restrict__ offs,
                                               int* __restrict__ bsum) {
  __shared__ int buf[256];
  int i = blockIdx.x * 256 + threadIdx.x;
  int v = (i < NNODE) ? deg[i] : 0;
  buf[threadIdx.x] = v;
  __syncthreads();
  for (int off = 1; off < 256; off <<= 1) {
    int t = (threadIdx.x >= off) ? buf[threadIdx.x - off] : 0;
    __syncthreads();
    buf[threadIdx.x] += t;
    __syncthreads();
  }
  if (i < NNODE) offs[i + 1] = buf[threadIdx.x];
  if (threadIdx.x == 255) bsum[blockIdx.x] = buf[255];
  if (i == 0) offs[0] = 0;
}

__global__ __launch_bounds__(256) void k_scan2(int* __restrict__ bsum, int nb) {
  __shared__ int buf[256];
  int v = (threadIdx.x < nb) ? bsum[threadIdx.x] : 0;
  buf[threadIdx.x] = v;
  __syncthreads();
  for (int off = 1; off < 256; off <<= 1) {
    int t = (threadIdx.x >= off) ? buf[threadIdx.x - off] : 0;
    __syncthreads();
    buf[threadIdx.x] += t;
    __syncthreads();
  }
  if (threadIdx.x < nb) bsum[threadIdx.x] = buf[threadIdx.x] - v;
}

__global__ __launch_bounds__(256) void k_scan3(int* __restrict__ offs, const int* __restrict__ bsum) {
  int i = blockIdx.x * 256 + threadIdx.x;
  if (i < NNODE) offs[i + 1] += bsum[blockIdx.x];
}

__global__ __launch_bounds__(256) void k_fill(const int* __restrict__ ei, const int* __restrict__ offs,
                                              int* __restrict__ cur, int* __restrict__ csrc) {
  int t = blockIdx.x * 256 + threadIdx.x;
  if (t >= NTOT) return;
  int s, d;
  if (t < NEDGE) { s = ei[t]; d = ei[NEDGE + t]; }
  else { s = t - NEDGE; d = s; }
  int pos = offs[d] + atomicAdd(&cur[d], 1);
  csrc[pos] = s;
}

// ---------------- att prescale: attp = [0.6*log2e*att | 0.4*log2e*att] ----------------

__global__ __launch_bounds__(256) void k_attp(const float* __restrict__ att1, const float* __restrict__ att2,
                                              float* __restrict__ attp1, float* __restrict__ attp2) {
  int t = blockIdx.x * 256 + threadIdx.x;
  if (t < 512) {
    float a = att1[t] * 1.44269504f;
    attp1[t] = 0.6f * a;
    attp1[512 + t] = 0.4f * a;
  } else if (t < 768) {
    int c = t - 512;
    float a = att2[c] * 1.44269504f;
    attp2[c] = 0.6f * a;
    attp2[256 + c] = 0.4f * a;
  }
}

// ---------------- B pre-pack into MFMA fragment order ----------------

template<int K, int N>
__global__ __launch_bounds__(256) void k_pack(const float* __restrict__ Wl, const float* __restrict__ Wr,
                                              bf16* __restrict__ Bp) {
  constexpr int KS = K / 32;
  int t = blockIdx.x * 256 + threadIdx.x;
  if (t >= (N / 16) * KS * 64) return;
  int lane = t & 63;
  int ks = (t >> 6) % KS;
  int cb = t / (64 * KS);
  int col = cb * 16 + (lane & 15);
  int k0 = ks * 32 + (lane >> 4) * 8;
  const float* W = (col < N / 2) ? Wl : Wr;
  int c = (col < N / 2) ? col : col - N / 2;
  bf16* o = Bp + (size_t)t * 8;
#pragma unroll
  for (int j = 0; j < 8; ++j)
    o[j] = __float2bfloat16(W[(size_t)(k0 + j) * (N / 2) + c]);
}

// ---------------- MFMA dual GEMM (NF col-frags per wave; optional fused A-cast) ----------------

template<int K, int N, int NF, bool CVT>
__global__ __launch_bounds__(256) void k_mfma(const void* __restrict__ Aptr,
                                              const bf16* __restrict__ Bp,
                                              bf16* __restrict__ xl, bf16* __restrict__ xr,
                                              int n) {
  constexpr int KS = K / 32;
  const int lane = threadIdx.x & 63;
  const int wave = threadIdx.x >> 6;
  const int rb = blockIdx.x * 32;
  const int cb0 = blockIdx.y * (4 * NF) + wave * NF;
  const int r16 = lane & 15, kg = lane >> 4;

  bf16x8 a[2][KS];
#pragma unroll
  for (int mf = 0; mf < 2; ++mf) {
    int row = rb + 16 * mf + r16;
    if (row >= n) row = n - 1;
    if constexpr (CVT) {
      const float* pa = (const float*)Aptr + (size_t)row * K + kg * 8;
#pragma unroll
      for (int ks = 0; ks < KS; ++ks) {
        float4 f0 = *(const float4*)(pa + ks * 32);
        float4 f1 = *(const float4*)(pa + ks * 32 + 4);
        bf16x8 v;
        v[0] = __float2bfloat16(f0.x); v[1] = __float2bfloat16(f0.y);
        v[2] = __float2bfloat16(f0.z); v[3] = __float2bfloat16(f0.w);
        v[4] = __float2bfloat16(f1.x); v[5] = __float2bfloat16(f1.y);
        v[6] = __float2bfloat16(f1.z); v[7] = __float2bfloat16(f1.w);
        a[mf][ks] = v;
      }
    } else {
      const bf16* pa = (const bf16*)Aptr + (size_t)row * K + kg * 8;
#pragma unroll
      for (int ks = 0; ks < KS; ++ks)
        a[mf][ks] = *(const bf16x8*)(pa + ks * 32);
    }
  }

#pragma unroll
  for (int nf = 0; nf < NF; ++nf) {
    int cb = cb0 + nf;
    f32x4 acc0 = {0.f, 0.f, 0.f, 0.f}, acc1 = {0.f, 0.f, 0.f, 0.f};
    const bf16* pb = Bp + (size_t)cb * KS * 512 + lane * 8;
#pragma unroll
    for (int ks = 0; ks < KS; ++ks) {
      bf16x8 b = *(const bf16x8*)(pb + ks * 512);
      acc0 = __builtin_amdgcn_mfma_f32_16x16x32_bf16(a[0][ks], b, acc0, 0, 0, 0);
      acc1 = __builtin_amdgcn_mfma_f32_16x16x32_bf16(a[1][ks], b, acc1, 0, 0, 0);
    }
    int col = cb * 16 + r16;
    bf16* OUT; int c;
    if (col < N / 2) { OUT = xl; c = col; } else { OUT = xr; c = col - N / 2; }
#pragma unroll
    for (int reg = 0; reg < 4; ++reg) {
      int row0 = rb + kg * 4 + reg;
      if (row0 < n) OUT[(size_t)row0 * (N / 2) + c] = __float2bfloat16(acc0[reg]);
      int row1 = rb + 16 + kg * 4 + reg;
      if (row1 < n) OUT[(size_t)row1 * (N / 2) + c] = __float2bfloat16(acc1[reg]);
    }
  }
}

// ---------------- residual (fp32 vector; small) ----------------

__global__ __launch_bounds__(256) void k_residual(const float* __restrict__ X,
                                                  const float* __restrict__ W,
                                                  const float* __restrict__ b,
                                                  float* __restrict__ out, int n) {
  __shared__ float xs[8 * 128];
  int row0 = blockIdx.x * 8;
  for (int t = threadIdx.x; t < 8 * 128; t += 256) {
    int r = t >> 7;
    xs[t] = (row0 + r < n) ? X[(size_t)(row0 + r) * 128 + (t & 127)] : 0.f;
  }
  __syncthreads();
  int r = threadIdx.x >> 5, c = threadIdx.x & 31;
  float acc = 0.f;
  for (int k = 0; k < 128; ++k) acc += xs[r * 128 + k] * W[k * 32 + c];
  if (row0 + r < n) out[(size_t)(row0 + r) * 32 + c] = acc + b[c];
}

// ---------------- fused GATv2 layer (R9 structure: edge-split, DPP reduce) ----------------
// Block = W waves = ONE node; wave w handles edges beg+w, beg+w+W, ... (clamped prefetch).
// Lane l: head l>>3, channels (l&7)*VEC + [0..VEC). Rows loaded as NW=VEC/2 u32 words.
// bf16->f32: lo=asfloat(w<<16), hi=asfloat(w&0xffff0000). lrelu(t)*a = a6*t + a4*|t|
// with a6/a4 PRECOMPUTED (incl. 0.6/0.4 and log2e fold) in attp: wgt = v_exp_f32(s).
// Max-free softmax (validated R6-R10). DO NOT: unclamped pad-prefetch (R10: +50MB fetch),
// launch_bounds min-waves 3 (R10: occupancy regression). R9 operating point: VGPR 32,
// ~72% occ, 77us, co-saturated (VALU ~93%, mem ~3.3 TB/s).

template<int D, int VEC, int W, bool L1>
__global__ __launch_bounds__(64 * W, 2) void k_gat(const bf16* __restrict__ xl,
                                                   const bf16* __restrict__ xr,
                                                   const float* __restrict__ attp,
                                                   const int* __restrict__ csrc,
                                                   const int* __restrict__ offs,
                                                   const float* __restrict__ bias,
                                                   const float* __restrict__ resid,
                                                   bf16* __restrict__ out1,
                                                   float* __restrict__ out2) {
  constexpr int CH = D / 8;
  constexpr int NW = VEC / 2;
  constexpr unsigned ROWB = D * 2;
  typedef unsigned int uivec __attribute__((ext_vector_type(NW)));
  typedef float fvec __attribute__((ext_vector_type(VEC)));
  __shared__ float sden[W - 1][64];
  __shared__ float sacc[W - 1][64][VEC + 1];
  const int w    = threadIdx.x >> 6;
  const int lane = threadIdx.x & 63;
  const int node = blockIdx.x;
  const int beg = offs[node], end = offs[node + 1], last = end - 1;

  const unsigned loff = (unsigned)(lane * VEC) * 2u;
  const char* xlp = (const char*)xl + loff;

  // per-lane constants: precomputed att halves (loads) + xr slice
  fvec a6 = *(const fvec*)(attp + lane * VEC);
  fvec a4 = *(const fvec*)(attp + D + lane * VEC);
  fvec xrv;
  {
    uivec rw = *(const uivec*)((const char*)xr + (size_t)node * ROWB + loff);
#pragma unroll
    for (int p = 0; p < NW; ++p) {
      xrv[2 * p]     = __uint_as_float(rw[p] << 16);
      xrv[2 * p + 1] = __uint_as_float(rw[p] & 0xffff0000u);
    }
  }

  float den = 0.f;
  fvec acc;
#pragma unroll
  for (int j = 0; j < VEC; ++j) acc[j] = 0.f;

  // per-edge score partial (pre-reduce): converts row words into av, returns s
  auto escore = [&](uivec Wd, fvec& av) -> float {
    float s0 = 0.f, s1 = 0.f;
#pragma unroll
    for (int p = 0; p < NW; ++p) {
      av[2 * p]     = __uint_as_float(Wd[p] << 16);
      av[2 * p + 1] = __uint_as_float(Wd[p] & 0xffff0000u);
    }
#pragma unroll
    for (int j = 0; j < VEC; ++j) {
      float t = av[j] + xrv[j];
      s0 = fmaf(a6[j], t, s0);
      s1 = fmaf(a4[j], fabsf(t), s1);
    }
    return s0 + s1;
  };

  int i = beg + w;
  if (i < end) {
    uivec A0 = *(const uivec*)(xlp + (unsigned)csrc[i] * ROWB);
    int i1 = (i + W < end) ? i + W : last;
    uivec A1 = *(const uivec*)(xlp + (unsigned)csrc[i1] * ROWB);
    for (; i + W < end; i += 2 * W) {
      int i2 = (i + 2 * W < end) ? i + 2 * W : last;
      int i3 = (i + 3 * W < end) ? i + 3 * W : last;
      uivec B0 = *(const uivec*)(xlp + (unsigned)csrc[i2] * ROWB);
      uivec B1 = *(const uivec*)(xlp + (unsigned)csrc[i3] * ROWB);

      fvec av0, av1;
      float s0 = escore(A0, av0);
      float s1 = escore(A1, av1);
      s0 = dpp_add<0xB1>(s0);   s1 = dpp_add<0xB1>(s1);
      s0 = dpp_add<0x4E>(s0);   s1 = dpp_add<0x4E>(s1);
      s0 = dpp_add<0x141>(s0);  s1 = dpp_add<0x141>(s1);
      float w0, w1;
      asm("v_exp_f32 %0, %1" : "=v"(w0) : "v"(s0));
      asm("v_exp_f32 %0, %1" : "=v"(w1) : "v"(s1));
      den += w0;
      den += w1;
#pragma unroll
      for (int j = 0; j < VEC; ++j) {
        acc[j] = fmaf(w0, av0[j], acc[j]);
        acc[j] = fmaf(w1, av1[j], acc[j]);
      }
      A0 = B0; A1 = B1;
    }
    if (i < end) {   // tail single edge
      fvec av0;
      float s0 = escore(A0, av0);
      s0 = dpp_add<0xB1>(s0);
      s0 = dpp_add<0x4E>(s0);
      s0 = dpp_add<0x141>(s0);
      float w0;
      asm("v_exp_f32 %0, %1" : "=v"(w0) : "v"(s0));
      den += w0;
#pragma unroll
      for (int j = 0; j < VEC; ++j) acc[j] = fmaf(w0, av0[j], acc[j]);
    }
  }

  if (w > 0) {
    sden[w - 1][lane] = den;
#pragma unroll
    for (int j = 0; j < VEC; ++j) sacc[w - 1][lane][j] = acc[j];
  }
  __syncthreads();
  if (w == 0) {
#pragma unroll
    for (int ww = 0; ww < W - 1; ++ww) {
      den += sden[ww][lane];
#pragma unroll
      for (int j = 0; j < VEC; ++j) acc[j] += sacc[ww][lane][j];
    }
    const float inv = 1.f / den;
    fvec v;
#pragma unroll
    for (int j = 0; j < VEC; ++j) {
      float t = acc[j] * inv;
      t += __shfl_xor(t, 8);
      t += __shfl_xor(t, 16);
      t += __shfl_xor(t, 32);
      v[j] = t;
    }
    if (lane < 8) {
      int c0 = lane * VEC;
      if constexpr (L1) {
        bf16* o = out1 + (size_t)node * CH + c0;
#pragma unroll
        for (int j = 0; j < VEC; ++j) {
          float t = v[j] * 0.125f + bias[c0 + j];
          o[j] = __float2bfloat16(fmaxf(t, 0.f));
        }
      } else {
        float* o = out2 + (size_t)node * CH + c0;
        const float* rs = resid + (size_t)node * CH + c0;
#pragma unroll
        for (int j = 0; j < VEC; ++j)
          o[j] = v[j] * 0.125f + bias[c0 + j] + rs[j];
      }
    }
  }
}

// ---------------- launch ----------------

extern "C" void kernel_launch(void* const* d_in, const int* in_sizes, int n_in,
                              void* d_out, int out_size, void* d_ws, size_t ws_size,
                              hipStream_t stream) {
  const float* x      = (const float*)d_in[0];
  const int*   ei     = (const int*)d_in[1];
  const float* lin1_w = (const float*)d_in[3];
  const float* lin1_b = (const float*)d_in[4];
  const float* wl1    = (const float*)d_in[5];
  const float* wr1    = (const float*)d_in[6];
  const float* att1   = (const float*)d_in[7];
  const float* b1     = (const float*)d_in[8];
  const float* wl2    = (const float*)d_in[9];
  const float* wr2    = (const float*)d_in[10];
  const float* att2   = (const float*)d_in[11];
  const float* b2     = (const float*)d_in[12];
  float* out = (float*)d_out;

  char* p = (char*)d_ws;
  auto alloc = [&](size_t bytes) {
    char* r = p;
    p += (bytes + 255) & ~size_t(255);
    return r;
  };
  int*   offs  = (int*)alloc((NNODE + 1) * 4);
  int*   deg   = (int*)alloc(NNODE * 4);
  int*   cur   = (int*)alloc(NNODE * 4);
  int*   bsum  = (int*)alloc(SCANB * 4);
  int*   csrc  = (int*)alloc((size_t)NTOT * 4);
  bf16*  xl    = (bf16*)alloc((size_t)NNODE * 512 * 2);
  bf16*  xr    = (bf16*)alloc((size_t)NNODE * 512 * 2);
  bf16*  h1    = (bf16*)alloc((size_t)NNODE * 64 * 2);
  bf16*  Bp1   = (bf16*)alloc((size_t)128 * 1024 * 2);
  bf16*  Bp2   = (bf16*)alloc((size_t)64 * 512 * 2);
  float* attp1 = (float*)alloc(1024 * 4);
  float* attp2 = (float*)alloc(512 * 4);
  float* resid = (float*)alloc((size_t)NNODE * 32 * 4);

  (void)hipMemsetAsync(deg, 0, NNODE * 4, stream);
  (void)hipMemsetAsync(cur, 0, NNODE * 4, stream);

  // prep
  k_count<<<(NTOT + 255) / 256, 256, 0, stream>>>(ei, deg);
  k_scan1<<<SCANB, 256, 0, stream>>>(deg, offs, bsum);
  k_scan2<<<1, 256, 0, stream>>>(bsum, SCANB);
  k_scan3<<<SCANB, 256, 0, stream>>>(offs, bsum);
  k_fill<<<(NTOT + 255) / 256, 256, 0, stream>>>(ei, offs, cur, csrc);
  k_attp<<<3, 256, 0, stream>>>(att1, att2, attp1, attp2);
  k_pack<128, 1024><<<64, 256, 0, stream>>>(wl1, wr1, Bp1);
  k_pack<64, 512><<<16, 256, 0, stream>>>(wl2, wr2, Bp2);
  k_residual<<<NNODE / 8, 256, 0, stream>>>(x, lin1_w, lin1_b, resid, NNODE);

  // layer 1 (A-cast fused; NF=8 -> A fetched 2x instead of 4x)
  k_mfma<128, 1024, 8, true><<<dim3((NNODE + 31) / 32, 2), 256, 0, stream>>>(x, Bp1, xl, xr, NNODE);
  k_gat<512, 8, 4, true><<<NNODE, 256, 0, stream>>>(xl, xr, attp1, csrc, offs, b1, nullptr, h1, nullptr);

  // layer 2 (NF=8 -> single y-block, A fetched once)
  k_mfma<64, 512, 8, false><<<dim3((NNODE + 31) / 32, 1), 256, 0, stream>>>(h1, Bp2, xl, xr, NNODE);
  k_gat<256, 4, 4, false><<<NNODE, 256, 0, stream>>>(xl, xr, attp2, csrc, offs, b2, resid, nullptr, out);
}

// Round 12
// 294.282 us; speedup vs baseline: 1.1099x; 1.0977x over previous
//
#include <hip/hip_runtime.h>
#include <hip/hip_bf16.h>

#define NNODE 50000
#define NEDGE 400000
#define NTOT  450000   // NEDGE + NNODE self-loops
#define FDIM  128
#define HEADS 8
#define SCANB ((NNODE + 255) / 256)   // 196 blocks

typedef __bf16 bf16x8 __attribute__((ext_vector_type(8)));
typedef float  f32x4  __attribute__((ext_vector_type(4)));
typedef __hip_bfloat16 bf16;

// v_add with DPP cross-lane source: v + dpp(v). 0xB1=quad_perm[1,0,3,2](xor1),
// 0x4E=quad_perm[2,3,0,1](xor2), 0x141=row_half_mirror(xor4 after quad sums).
template<int CTRL>
static __device__ __forceinline__ float dpp_add(float v) {
  int x = __builtin_amdgcn_update_dpp(0, __float_as_int(v), CTRL, 0xf, 0xf, true);
  return v + __int_as_float(x);
}

// ---------------- CSR build ----------------

__global__ __launch_bounds__(256) void k_count(const int* __restrict__ ei, int* __restrict__ deg) {
  int t = blockIdx.x * 256 + threadIdx.x;
  if (t >= NTOT) return;
  int d = (t < NEDGE) ? ei[NEDGE + t] : (t - NEDGE);
  atomicAdd(&deg[d], 1);
}

__global__ __launch_bounds__(256) void k_scan1(const int* __restrict__ deg, int* __restrict__ offs,
                                               int* __restrict__ bsum) {
  __shared__ int buf[256];
  int i = blockIdx.x * 256 + threadIdx.x;
  int v = (i < NNODE) ? deg[i] : 0;
  buf[threadIdx.x] = v;
  __syncthreads();
  for (int off = 1; off < 256; off <<= 1) {
    int t = (threadIdx.x >= off) ? buf[threadIdx.x - off] : 0;
    __syncthreads();
    buf[threadIdx.x] += t;
    __syncthreads();
  }
  if (i < NNODE) offs[i + 1] = buf[threadIdx.x];
  if (threadIdx.x == 255) bsum[blockIdx.x] = buf[255];
  if (i == 0) offs[0] = 0;
}

__global__ __launch_bounds__(256) void k_scan2(int* __restrict__ bsum, int nb) {
  __shared__ int buf[256];
  int v = (threadIdx.x < nb) ? bsum[threadIdx.x] : 0;
  buf[threadIdx.x] = v;
  __syncthreads();
  for (int off = 1; off < 256; off <<= 1) {
    int t = (threadIdx.x >= off) ? buf[threadIdx.x - off] : 0;
    __syncthreads();
    buf[threadIdx.x] += t;
    __syncthreads();
  }
  if (threadIdx.x < nb) bsum[threadIdx.x] = buf[threadIdx.x] - v;
}

__global__ __launch_bounds__(256) void k_scan3(int* __restrict__ offs, const int* __restrict__ bsum) {
  int i = blockIdx.x * 256 + threadIdx.x;
  if (i < NNODE) offs[i + 1] += bsum[blockIdx.x];
}

__global__ __launch_bounds__(256) void k_fill(const int* __restrict__ ei, const int* __restrict__ offs,
                                              int* __restrict__ cur, int* __restrict__ csrc) {
  int t = blockIdx.x * 256 + threadIdx.x;
  if (t >= NTOT) return;
  int s, d;
  if (t < NEDGE) { s = ei[t]; d = ei[NEDGE + t]; }
  else { s = t - NEDGE; d = s; }
  int pos = offs[d] + atomicAdd(&cur[d], 1);
  csrc[pos] = s;
}

// ---------------- B pre-pack into MFMA fragment order ----------------

template<int K, int N>
__global__ __launch_bounds__(256) void k_pack(const float* __restrict__ Wl, const float* __restrict__ Wr,
                                              bf16* __restrict__ Bp) {
  constexpr int KS = K / 32;
  int t = blockIdx.x * 256 + threadIdx.x;
  if (t >= (N / 16) * KS * 64) return;
  int lane = t & 63;
  int ks = (t >> 6) % KS;
  int cb = t / (64 * KS);
  int col = cb * 16 + (lane & 15);
  int k0 = ks * 32 + (lane >> 4) * 8;
  const float* W = (col < N / 2) ? Wl : Wr;
  int c = (col < N / 2) ? col : col - N / 2;
  bf16* o = Bp + (size_t)t * 8;
#pragma unroll
  for (int j = 0; j < 8; ++j)
    o[j] = __float2bfloat16(W[(size_t)(k0 + j) * (N / 2) + c]);
}

// ---------------- MFMA dual GEMM (NF col-frags per wave; optional fused A-cast) ----------------

template<int K, int N, int NF, bool CVT>
__global__ __launch_bounds__(256) void k_mfma(const void* __restrict__ Aptr,
                                              const bf16* __restrict__ Bp,
                                              bf16* __restrict__ xl, bf16* __restrict__ xr,
                                              int n) {
  constexpr int KS = K / 32;
  const int lane = threadIdx.x & 63;
  const int wave = threadIdx.x >> 6;
  const int rb = blockIdx.x * 32;
  const int cb0 = blockIdx.y * (4 * NF) + wave * NF;
  const int r16 = lane & 15, kg = lane >> 4;

  bf16x8 a[2][KS];
#pragma unroll
  for (int mf = 0; mf < 2; ++mf) {
    int row = rb + 16 * mf + r16;
    if (row >= n) row = n - 1;
    if constexpr (CVT) {
      const float* pa = (const float*)Aptr + (size_t)row * K + kg * 8;
#pragma unroll
      for (int ks = 0; ks < KS; ++ks) {
        float4 f0 = *(const float4*)(pa + ks * 32);
        float4 f1 = *(const float4*)(pa + ks * 32 + 4);
        bf16x8 v;
        v[0] = __float2bfloat16(f0.x); v[1] = __float2bfloat16(f0.y);
        v[2] = __float2bfloat16(f0.z); v[3] = __float2bfloat16(f0.w);
        v[4] = __float2bfloat16(f1.x); v[5] = __float2bfloat16(f1.y);
        v[6] = __float2bfloat16(f1.z); v[7] = __float2bfloat16(f1.w);
        a[mf][ks] = v;
      }
    } else {
      const bf16* pa = (const bf16*)Aptr + (size_t)row * K + kg * 8;
#pragma unroll
      for (int ks = 0; ks < KS; ++ks)
        a[mf][ks] = *(const bf16x8*)(pa + ks * 32);
    }
  }

#pragma unroll
  for (int nf = 0; nf < NF; ++nf) {
    int cb = cb0 + nf;
    f32x4 acc0 = {0.f, 0.f, 0.f, 0.f}, acc1 = {0.f, 0.f, 0.f, 0.f};
    const bf16* pb = Bp + (size_t)cb * KS * 512 + lane * 8;
#pragma unroll
    for (int ks = 0; ks < KS; ++ks) {
      bf16x8 b = *(const bf16x8*)(pb + ks * 512);
      acc0 = __builtin_amdgcn_mfma_f32_16x16x32_bf16(a[0][ks], b, acc0, 0, 0, 0);
      acc1 = __builtin_amdgcn_mfma_f32_16x16x32_bf16(a[1][ks], b, acc1, 0, 0, 0);
    }
    int col = cb * 16 + r16;
    bf16* OUT; int c;
    if (col < N / 2) { OUT = xl; c = col; } else { OUT = xr; c = col - N / 2; }
#pragma unroll
    for (int reg = 0; reg < 4; ++reg) {
      int row0 = rb + kg * 4 + reg;
      if (row0 < n) OUT[(size_t)row0 * (N / 2) + c] = __float2bfloat16(acc0[reg]);
      int row1 = rb + 16 + kg * 4 + reg;
      if (row1 < n) OUT[(size_t)row1 * (N / 2) + c] = __float2bfloat16(acc1[reg]);
    }
  }
}

// ---------------- residual (fp32 vector; small) ----------------

__global__ __launch_bounds__(256) void k_residual(const float* __restrict__ X,
                                                  const float* __restrict__ W,
                                                  const float* __restrict__ b,
                                                  float* __restrict__ out, int n) {
  __shared__ float xs[8 * 128];
  int row0 = blockIdx.x * 8;
  for (int t = threadIdx.x; t < 8 * 128; t += 256) {
    int r = t >> 7;
    xs[t] = (row0 + r < n) ? X[(size_t)(row0 + r) * 128 + (t & 127)] : 0.f;
  }
  __syncthreads();
  int r = threadIdx.x >> 5, c = threadIdx.x & 31;
  float acc = 0.f;
  for (int k = 0; k < 128; ++k) acc += xs[r * 128 + k] * W[k * 32 + c];
  if (row0 + r < n) out[(size_t)(row0 + r) * 32 + c] = acc + b[c];
}

// ---------------- fused GATv2 layer (VERBATIM R8 proposal: 77us, VGPR 32, occ 72%) ----------------
// Block = W waves = ONE node; wave w handles edges beg+w, beg+w+W, ...
// Lane l: head l>>3, channels (l&7)*VEC + [0..VEC). Rows loaded as NW=VEC/2 u32 words.
// bf16->f32: lo = asfloat(w<<16), hi = asfloat(w & 0xffff0000)  (1 VALU/elem).
// lrelu(t)*a = (0.6a)t + (0.4a)|t|; att prescaled by log2(e) so wgt = v_exp_f32(s).
// Score reduce over 8 lanes via DPP adds. Max-free softmax (validated R6-R11).
// DO NOT EDIT: every register-allocation "improvement" attempted (R9 ext_vector+pad
// prefetch, R11 attp-load+fvec& lambda) regressed gat1 77 -> 94/104 us via VGPR/occ
// or fetch changes. This exact source is the proven operating point.

template<int D, int VEC, int W, bool L1>
__global__ __launch_bounds__(64 * W, 2) void k_gat(const bf16* __restrict__ xl,
                                                   const bf16* __restrict__ xr,
                                                   const float* __restrict__ att,
                                                   const int* __restrict__ csrc,
                                                   const int* __restrict__ offs,
                                                   const float* __restrict__ bias,
                                                   const float* __restrict__ resid,
                                                   bf16* __restrict__ out1,
                                                   float* __restrict__ out2) {
  constexpr int CH = D / 8;
  constexpr int NW = VEC / 2;
  constexpr unsigned ROWB = D * 2;
  typedef unsigned int uivec __attribute__((ext_vector_type(NW)));
  __shared__ float sden[W - 1][64];
  __shared__ float sacc[W - 1][64][VEC + 1];
  const int w    = threadIdx.x >> 6;
  const int lane = threadIdx.x & 63;
  const int node = blockIdx.x;
  const int beg = offs[node], end = offs[node + 1], last = end - 1;

  const unsigned loff = (unsigned)(lane * VEC) * 2u;
  const char* xlp = (const char*)xl + loff;

  // per-lane constants: prescaled att halves + xr slice
  float a6[VEC], a4[VEC], xrv[VEC];
  {
    const float* pa = att + lane * VEC;
    const unsigned int* rw = (const unsigned int*)((const char*)xr + (size_t)node * ROWB + loff);
#pragma unroll
    for (int p = 0; p < NW; ++p) {
      unsigned int rv = rw[p];
      xrv[2 * p]     = __uint_as_float(rv << 16);
      xrv[2 * p + 1] = __uint_as_float(rv & 0xffff0000u);
    }
#pragma unroll
    for (int j = 0; j < VEC; ++j) {
      float a = pa[j] * 1.44269504f;   // fold exp->exp2
      a6[j] = 0.6f * a;
      a4[j] = 0.4f * a;
    }
  }

  float den = 0.f;
  float acc[VEC];
#pragma unroll
  for (int j = 0; j < VEC; ++j) acc[j] = 0.f;

  // per-edge score partial (pre-reduce): converts row words, returns s; av filled
  auto escore = [&](uivec Wd, float* av) -> float {
    float s0 = 0.f, s1 = 0.f;
#pragma unroll
    for (int p = 0; p < NW; ++p) {
      av[2 * p]     = __uint_as_float(Wd[p] << 16);
      av[2 * p + 1] = __uint_as_float(Wd[p] & 0xffff0000u);
    }
#pragma unroll
    for (int j = 0; j < VEC; ++j) {
      float t = av[j] + xrv[j];
      s0 = fmaf(a6[j], t, s0);
      s1 = fmaf(a4[j], fabsf(t), s1);
    }
    return s0 + s1;
  };

  int i = beg + w;
  if (i < end) {
    uivec A0 = *(const uivec*)(xlp + (unsigned)csrc[i] * ROWB);
    int i1 = (i + W < end) ? i + W : last;
    uivec A1 = *(const uivec*)(xlp + (unsigned)csrc[i1] * ROWB);
    for (; i + W < end; i += 2 * W) {
      int i2 = (i + 2 * W < end) ? i + 2 * W : last;
      int i3 = (i + 3 * W < end) ? i + 3 * W : last;
      uivec B0 = *(const uivec*)(xlp + (unsigned)csrc[i2] * ROWB);
      uivec B1 = *(const uivec*)(xlp + (unsigned)csrc[i3] * ROWB);

      float av0[VEC], av1[VEC];
      float s0 = escore(A0, av0);
      float s1 = escore(A1, av1);
      s0 = dpp_add<0xB1>(s0);   s1 = dpp_add<0xB1>(s1);    // xor1
      s0 = dpp_add<0x4E>(s0);   s1 = dpp_add<0x4E>(s1);    // xor2
      s0 = dpp_add<0x141>(s0);  s1 = dpp_add<0x141>(s1);   // xor4 (half-mirror)
      float w0, w1;
      asm("v_exp_f32 %0, %1" : "=v"(w0) : "v"(s0));   // 2^s = exp(sc)
      asm("v_exp_f32 %0, %1" : "=v"(w1) : "v"(s1));
      den += w0;
      den += w1;
#pragma unroll
      for (int j = 0; j < VEC; ++j) {
        acc[j] = fmaf(w0, av0[j], acc[j]);
        acc[j] = fmaf(w1, av1[j], acc[j]);
      }
      A0 = B0; A1 = B1;
    }
    if (i < end) {   // tail single edge
      float av0[VEC];
      float s0 = escore(A0, av0);
      s0 = dpp_add<0xB1>(s0);
      s0 = dpp_add<0x4E>(s0);
      s0 = dpp_add<0x141>(s0);
      float w0;
      asm("v_exp_f32 %0, %1" : "=v"(w0) : "v"(s0));
      den += w0;
#pragma unroll
      for (int j = 0; j < VEC; ++j) acc[j] = fmaf(w0, av0[j], acc[j]);
    }
  }

  if (w > 0) {
    sden[w - 1][lane] = den;
#pragma unroll
    for (int j = 0; j < VEC; ++j) sacc[w - 1][lane][j] = acc[j];
  }
  __syncthreads();
  if (w == 0) {
#pragma unroll
    for (int ww = 0; ww < W - 1; ++ww) {
      den += sden[ww][lane];
#pragma unroll
      for (int j = 0; j < VEC; ++j) acc[j] += sacc[ww][lane][j];
    }
    const float inv = 1.f / den;
    float v[VEC];
#pragma unroll
    for (int j = 0; j < VEC; ++j) {
      float t = acc[j] * inv;
      t += __shfl_xor(t, 8);
      t += __shfl_xor(t, 16);
      t += __shfl_xor(t, 32);
      v[j] = t;
    }
    if (lane < 8) {
      int c0 = lane * VEC;
      if constexpr (L1) {
        bf16* o = out1 + (size_t)node * CH + c0;
#pragma unroll
        for (int j = 0; j < VEC; ++j) {
          float t = v[j] * 0.125f + bias[c0 + j];
          o[j] = __float2bfloat16(fmaxf(t, 0.f));
        }
      } else {
        float* o = out2 + (size_t)node * CH + c0;
        const float* rs = resid + (size_t)node * CH + c0;
#pragma unroll
        for (int j = 0; j < VEC; ++j)
          o[j] = v[j] * 0.125f + bias[c0 + j] + rs[j];
      }
    }
  }
}

// ---------------- launch ----------------

extern "C" void kernel_launch(void* const* d_in, const int* in_sizes, int n_in,
                              void* d_out, int out_size, void* d_ws, size_t ws_size,
                              hipStream_t stream) {
  const float* x      = (const float*)d_in[0];
  const int*   ei     = (const int*)d_in[1];
  const float* lin1_w = (const float*)d_in[3];
  const float* lin1_b = (const float*)d_in[4];
  const float* wl1    = (const float*)d_in[5];
  const float* wr1    = (const float*)d_in[6];
  const float* att1   = (const float*)d_in[7];
  const float* b1     = (const float*)d_in[8];
  const float* wl2    = (const float*)d_in[9];
  const float* wr2    = (const float*)d_in[10];
  const float* att2   = (const float*)d_in[11];
  const float* b2     = (const float*)d_in[12];
  float* out = (float*)d_out;

  char* p = (char*)d_ws;
  auto alloc = [&](size_t bytes) {
    char* r = p;
    p += (bytes + 255) & ~size_t(255);
    return r;
  };
  int*   offs  = (int*)alloc((NNODE + 1) * 4);
  int*   deg   = (int*)alloc(NNODE * 4);
  int*   cur   = (int*)alloc(NNODE * 4);
  int*   bsum  = (int*)alloc(SCANB * 4);
  int*   csrc  = (int*)alloc((size_t)NTOT * 4);
  bf16*  xl    = (bf16*)alloc((size_t)NNODE * 512 * 2);
  bf16*  xr    = (bf16*)alloc((size_t)NNODE * 512 * 2);
  bf16*  h1    = (bf16*)alloc((size_t)NNODE * 64 * 2);
  bf16*  Bp1   = (bf16*)alloc((size_t)128 * 1024 * 2);
  bf16*  Bp2   = (bf16*)alloc((size_t)64 * 512 * 2);
  float* resid = (float*)alloc((size_t)NNODE * 32 * 4);

  (void)hipMemsetAsync(deg, 0, NNODE * 4, stream);
  (void)hipMemsetAsync(cur, 0, NNODE * 4, stream);

  // prep
  k_count<<<(NTOT + 255) / 256, 256, 0, stream>>>(ei, deg);
  k_scan1<<<SCANB, 256, 0, stream>>>(deg, offs, bsum);
  k_scan2<<<1, 256, 0, stream>>>(bsum, SCANB);
  k_scan3<<<SCANB, 256, 0, stream>>>(offs, bsum);
  k_fill<<<(NTOT + 255) / 256, 256, 0, stream>>>(ei, offs, cur, csrc);
  k_pack<128, 1024><<<64, 256, 0, stream>>>(wl1, wr1, Bp1);
  k_pack<64, 512><<<16, 256, 0, stream>>>(wl2, wr2, Bp2);
  k_residual<<<NNODE / 8, 256, 0, stream>>>(x, lin1_w, lin1_b, resid, NNODE);

  // layer 1 (A-cast fused into MFMA; NF=8 -> A fetched 2x instead of 4x)
  k_mfma<128, 1024, 8, true><<<dim3((NNODE + 31) / 32, 2), 256, 0, stream>>>(x, Bp1, xl, xr, NNODE);
  k_gat<512, 8, 4, true><<<NNODE, 256, 0, stream>>>(xl, xr, att1, csrc, offs, b1, nullptr, h1, nullptr);

  // layer 2 (NF=8 -> single y-block)
  k_mfma<64, 512, 8, false><<<dim3((NNODE + 31) / 32, 1), 256, 0, stream>>>(h1, Bp2, xl, xr, NNODE);
  k_gat<256, 4, 4, false><<<NNODE, 256, 0, stream>>>(xl, xr, att2, csrc, offs, b2, resid, nullptr, out);
}

// Round 13
// 272.329 us; speedup vs baseline: 1.1994x; 1.0806x over previous
//
#include <hip/hip_runtime.h>
#include <hip/hip_bf16.h>

#define NNODE 50000
#define NEDGE 400000
#define NTOT  450000   // NEDGE + NNODE self-loops
#define FDIM  128
#define HEADS 8
#define SCANB ((NNODE + 255) / 256)   // 196 blocks

typedef __bf16 bf16x8 __attribute__((ext_vector_type(8)));
typedef float  f32x4  __attribute__((ext_vector_type(4)));
typedef __hip_bfloat16 bf16;

// v_add with DPP cross-lane source: v + dpp(v). 0xB1=quad_perm[1,0,3,2](xor1),
// 0x4E=quad_perm[2,3,0,1](xor2), 0x141=row_half_mirror(xor4 after quad sums).
template<int CTRL>
static __device__ __forceinline__ float dpp_add(float v) {
  int x = __builtin_amdgcn_update_dpp(0, __float_as_int(v), CTRL, 0xf, 0xf, true);
  return v + __int_as_float(x);
}

// ---------------- CSR build ----------------

__global__ __launch_bounds__(256) void k_count(const int* __restrict__ ei, int* __restrict__ deg) {
  int t = blockIdx.x * 256 + threadIdx.x;
  if (t >= NTOT) return;
  int d = (t < NEDGE) ? ei[NEDGE + t] : (t - NEDGE);
  atomicAdd(&deg[d], 1);
}

__global__ __launch_bounds__(256) void k_scan1(const int* __restrict__ deg, int* __restrict__ offs,
                                               int* __restrict__ bsum) {
  __shared__ int buf[256];
  int i = blockIdx.x * 256 + threadIdx.x;
  int v = (i < NNODE) ? deg[i] : 0;
  buf[threadIdx.x] = v;
  __syncthreads();
  for (int off = 1; off < 256; off <<= 1) {
    int t = (threadIdx.x >= off) ? buf[threadIdx.x - off] : 0;
    __syncthreads();
    buf[threadIdx.x] += t;
    __syncthreads();
  }
  if (i < NNODE) offs[i + 1] = buf[threadIdx.x];
  if (threadIdx.x == 255) bsum[blockIdx.x] = buf[255];
  if (i == 0) offs[0] = 0;
}

__global__ __launch_bounds__(256) void k_scan2(int* __restrict__ bsum, int nb) {
  __shared__ int buf[256];
  int v = (threadIdx.x < nb) ? bsum[threadIdx.x] : 0;
  buf[threadIdx.x] = v;
  __syncthreads();
  for (int off = 1; off < 256; off <<= 1) {
    int t = (threadIdx.x >= off) ? buf[threadIdx.x - off] : 0;
    __syncthreads();
    buf[threadIdx.x] += t;
    __syncthreads();
  }
  if (threadIdx.x < nb) bsum[threadIdx.x] = buf[threadIdx.x] - v;
}

__global__ __launch_bounds__(256) void k_scan3(int* __restrict__ offs, const int* __restrict__ bsum) {
  int i = blockIdx.x * 256 + threadIdx.x;
  if (i < NNODE) offs[i + 1] += bsum[blockIdx.x];
}

__global__ __launch_bounds__(256) void k_fill(const int* __restrict__ ei, const int* __restrict__ offs,
                                              int* __restrict__ cur, int* __restrict__ csrc) {
  int t = blockIdx.x * 256 + threadIdx.x;
  if (t >= NTOT) return;
  int s, d;
  if (t < NEDGE) { s = ei[t]; d = ei[NEDGE + t]; }
  else { s = t - NEDGE; d = s; }
  int pos = offs[d] + atomicAdd(&cur[d], 1);
  csrc[pos] = s;
}

// ---------------- B pre-pack into MFMA fragment order ----------------

template<int K, int N>
__global__ __launch_bounds__(256) void k_pack(const float* __restrict__ Wl, const float* __restrict__ Wr,
                                              bf16* __restrict__ Bp) {
  constexpr int KS = K / 32;
  int t = blockIdx.x * 256 + threadIdx.x;
  if (t >= (N / 16) * KS * 64) return;
  int lane = t & 63;
  int ks = (t >> 6) % KS;
  int cb = t / (64 * KS);
  int col = cb * 16 + (lane & 15);
  int k0 = ks * 32 + (lane >> 4) * 8;
  const float* W = (col < N / 2) ? Wl : Wr;
  int c = (col < N / 2) ? col : col - N / 2;
  bf16* o = Bp + (size_t)t * 8;
#pragma unroll
  for (int j = 0; j < 8; ++j)
    o[j] = __float2bfloat16(W[(size_t)(k0 + j) * (N / 2) + c]);
}

// ---------------- MFMA dual GEMM (NF col-frags per wave; optional fused A-cast) ----------------

template<int K, int N, int NF, bool CVT>
__global__ __launch_bounds__(256) void k_mfma(const void* __restrict__ Aptr,
                                              const bf16* __restrict__ Bp,
                                              bf16* __restrict__ xl, bf16* __restrict__ xr,
                                              int n) {
  constexpr int KS = K / 32;
  const int lane = threadIdx.x & 63;
  const int wave = threadIdx.x >> 6;
  const int rb = blockIdx.x * 32;
  const int cb0 = blockIdx.y * (4 * NF) + wave * NF;
  const int r16 = lane & 15, kg = lane >> 4;

  bf16x8 a[2][KS];
#pragma unroll
  for (int mf = 0; mf < 2; ++mf) {
    int row = rb + 16 * mf + r16;
    if (row >= n) row = n - 1;
    if constexpr (CVT) {
      const float* pa = (const float*)Aptr + (size_t)row * K + kg * 8;
#pragma unroll
      for (int ks = 0; ks < KS; ++ks) {
        float4 f0 = *(const float4*)(pa + ks * 32);
        float4 f1 = *(const float4*)(pa + ks * 32 + 4);
        bf16x8 v;
        v[0] = __float2bfloat16(f0.x); v[1] = __float2bfloat16(f0.y);
        v[2] = __float2bfloat16(f0.z); v[3] = __float2bfloat16(f0.w);
        v[4] = __float2bfloat16(f1.x); v[5] = __float2bfloat16(f1.y);
        v[6] = __float2bfloat16(f1.z); v[7] = __float2bfloat16(f1.w);
        a[mf][ks] = v;
      }
    } else {
      const bf16* pa = (const bf16*)Aptr + (size_t)row * K + kg * 8;
#pragma unroll
      for (int ks = 0; ks < KS; ++ks)
        a[mf][ks] = *(const bf16x8*)(pa + ks * 32);
    }
  }

#pragma unroll
  for (int nf = 0; nf < NF; ++nf) {
    int cb = cb0 + nf;
    f32x4 acc0 = {0.f, 0.f, 0.f, 0.f}, acc1 = {0.f, 0.f, 0.f, 0.f};
    const bf16* pb = Bp + (size_t)cb * KS * 512 + lane * 8;
#pragma unroll
    for (int ks = 0; ks < KS; ++ks) {
      bf16x8 b = *(const bf16x8*)(pb + ks * 512);
      acc0 = __builtin_amdgcn_mfma_f32_16x16x32_bf16(a[0][ks], b, acc0, 0, 0, 0);
      acc1 = __builtin_amdgcn_mfma_f32_16x16x32_bf16(a[1][ks], b, acc1, 0, 0, 0);
    }
    int col = cb * 16 + r16;
    bf16* OUT; int c;
    if (col < N / 2) { OUT = xl; c = col; } else { OUT = xr; c = col - N / 2; }
#pragma unroll
    for (int reg = 0; reg < 4; ++reg) {
      int row0 = rb + kg * 4 + reg;
      if (row0 < n) OUT[(size_t)row0 * (N / 2) + c] = __float2bfloat16(acc0[reg]);
      int row1 = rb + 16 + kg * 4 + reg;
      if (row1 < n) OUT[(size_t)row1 * (N / 2) + c] = __float2bfloat16(acc1[reg]);
    }
  }
}

// ---------------- residual (fp32 vector; small) ----------------

__global__ __launch_bounds__(256) void k_residual(const float* __restrict__ X,
                                                  const float* __restrict__ W,
                                                  const float* __restrict__ b,
                                                  float* __restrict__ out, int n) {
  __shared__ float xs[8 * 128];
  int row0 = blockIdx.x * 8;
  for (int t = threadIdx.x; t < 8 * 128; t += 256) {
    int r = t >> 7;
    xs[t] = (row0 + r < n) ? X[(size_t)(row0 + r) * 128 + (t & 127)] : 0.f;
  }
  __syncthreads();
  int r = threadIdx.x >> 5, c = threadIdx.x & 31;
  float acc = 0.f;
  for (int k = 0; k < 128; ++k) acc += xs[r * 128 + k] * W[k * 32 + c];
  if (row0 + r < n) out[(size_t)(row0 + r) * 32 + c] = acc + b[c];
}

// ---------------- fused GATv2 layer (VERBATIM R8 proposal body: proven operating point) ----------------
// Block = W waves = ONE node; wave w handles edges beg+w, beg+w+W, ...
// Lane l: head l>>3, channels (l&7)*VEC + [0..VEC). Rows loaded as NW=VEC/2 u32 words.
// bf16->f32: lo = asfloat(w<<16), hi = asfloat(w & 0xffff0000)  (1 VALU/elem).
// lrelu(t)*a = (0.6a)t + (0.4a)|t|; att prescaled by log2(e) so wgt = v_exp_f32(s).
// Score reduce over 8 lanes via DPP adds. Max-free softmax (validated R6-R12).
// DO NOT EDIT BODY: every register-allocation "improvement" attempted (R9, R10, R11)
// regressed gat1 77 -> 94/104 us. W is a template param (R13: W=2 — avg deg 9 means
// W=4 waves saw only 2.25 edges each; per-node fixed cost was ~35% of VALU).

template<int D, int VEC, int W, bool L1>
__global__ __launch_bounds__(64 * W, 2) void k_gat(const bf16* __restrict__ xl,
                                                   const bf16* __restrict__ xr,
                                                   const float* __restrict__ att,
                                                   const int* __restrict__ csrc,
                                                   const int* __restrict__ offs,
                                                   const float* __restrict__ bias,
                                                   const float* __restrict__ resid,
                                                   bf16* __restrict__ out1,
                                                   float* __restrict__ out2) {
  constexpr int CH = D / 8;
  constexpr int NW = VEC / 2;
  constexpr unsigned ROWB = D * 2;
  typedef unsigned int uivec __attribute__((ext_vector_type(NW)));
  __shared__ float sden[W - 1][64];
  __shared__ float sacc[W - 1][64][VEC + 1];
  const int w    = threadIdx.x >> 6;
  const int lane = threadIdx.x & 63;
  const int node = blockIdx.x;
  const int beg = offs[node], end = offs[node + 1], last = end - 1;

  const unsigned loff = (unsigned)(lane * VEC) * 2u;
  const char* xlp = (const char*)xl + loff;

  // per-lane constants: prescaled att halves + xr slice
  float a6[VEC], a4[VEC], xrv[VEC];
  {
    const float* pa = att + lane * VEC;
    const unsigned int* rw = (const unsigned int*)((const char*)xr + (size_t)node * ROWB + loff);
#pragma unroll
    for (int p = 0; p < NW; ++p) {
      unsigned int rv = rw[p];
      xrv[2 * p]     = __uint_as_float(rv << 16);
      xrv[2 * p + 1] = __uint_as_float(rv & 0xffff0000u);
    }
#pragma unroll
    for (int j = 0; j < VEC; ++j) {
      float a = pa[j] * 1.44269504f;   // fold exp->exp2
      a6[j] = 0.6f * a;
      a4[j] = 0.4f * a;
    }
  }

  float den = 0.f;
  float acc[VEC];
#pragma unroll
  for (int j = 0; j < VEC; ++j) acc[j] = 0.f;

  // per-edge score partial (pre-reduce): converts row words, returns s; av filled
  auto escore = [&](uivec Wd, float* av) -> float {
    float s0 = 0.f, s1 = 0.f;
#pragma unroll
    for (int p = 0; p < NW; ++p) {
      av[2 * p]     = __uint_as_float(Wd[p] << 16);
      av[2 * p + 1] = __uint_as_float(Wd[p] & 0xffff0000u);
    }
#pragma unroll
    for (int j = 0; j < VEC; ++j) {
      float t = av[j] + xrv[j];
      s0 = fmaf(a6[j], t, s0);
      s1 = fmaf(a4[j], fabsf(t), s1);
    }
    return s0 + s1;
  };

  int i = beg + w;
  if (i < end) {
    uivec A0 = *(const uivec*)(xlp + (unsigned)csrc[i] * ROWB);
    int i1 = (i + W < end) ? i + W : last;
    uivec A1 = *(const uivec*)(xlp + (unsigned)csrc[i1] * ROWB);
    for (; i + W < end; i += 2 * W) {
      int i2 = (i + 2 * W < end) ? i + 2 * W : last;
      int i3 = (i + 3 * W < end) ? i + 3 * W : last;
      uivec B0 = *(const uivec*)(xlp + (unsigned)csrc[i2] * ROWB);
      uivec B1 = *(const uivec*)(xlp + (unsigned)csrc[i3] * ROWB);

      float av0[VEC], av1[VEC];
      float s0 = escore(A0, av0);
      float s1 = escore(A1, av1);
      s0 = dpp_add<0xB1>(s0);   s1 = dpp_add<0xB1>(s1);    // xor1
      s0 = dpp_add<0x4E>(s0);   s1 = dpp_add<0x4E>(s1);    // xor2
      s0 = dpp_add<0x141>(s0);  s1 = dpp_add<0x141>(s1);   // xor4 (half-mirror)
      float w0, w1;
      asm("v_exp_f32 %0, %1" : "=v"(w0) : "v"(s0));   // 2^s = exp(sc)
      asm("v_exp_f32 %0, %1" : "=v"(w1) : "v"(s1));
      den += w0;
      den += w1;
#pragma unroll
      for (int j = 0; j < VEC; ++j) {
        acc[j] = fmaf(w0, av0[j], acc[j]);
        acc[j] = fmaf(w1, av1[j], acc[j]);
      }
      A0 = B0; A1 = B1;
    }
    if (i < end) {   // tail single edge
      float av0[VEC];
      float s0 = escore(A0, av0);
      s0 = dpp_add<0xB1>(s0);
      s0 = dpp_add<0x4E>(s0);
      s0 = dpp_add<0x141>(s0);
      float w0;
      asm("v_exp_f32 %0, %1" : "=v"(w0) : "v"(s0));
      den += w0;
#pragma unroll
      for (int j = 0; j < VEC; ++j) acc[j] = fmaf(w0, av0[j], acc[j]);
    }
  }

  if (w > 0) {
    sden[w - 1][lane] = den;
#pragma unroll
    for (int j = 0; j < VEC; ++j) sacc[w - 1][lane][j] = acc[j];
  }
  __syncthreads();
  if (w == 0) {
#pragma unroll
    for (int ww = 0; ww < W - 1; ++ww) {
      den += sden[ww][lane];
#pragma unroll
      for (int j = 0; j < VEC; ++j) acc[j] += sacc[ww][lane][j];
    }
    const float inv = 1.f / den;
    float v[VEC];
#pragma unroll
    for (int j = 0; j < VEC; ++j) {
      float t = acc[j] * inv;
      t += __shfl_xor(t, 8);
      t += __shfl_xor(t, 16);
      t += __shfl_xor(t, 32);
      v[j] = t;
    }
    if (lane < 8) {
      int c0 = lane * VEC;
      if constexpr (L1) {
        bf16* o = out1 + (size_t)node * CH + c0;
#pragma unroll
        for (int j = 0; j < VEC; ++j) {
          float t = v[j] * 0.125f + bias[c0 + j];
          o[j] = __float2bfloat16(fmaxf(t, 0.f));
        }
      } else {
        float* o = out2 + (size_t)node * CH + c0;
        const float* rs = resid + (size_t)node * CH + c0;
#pragma unroll
        for (int j = 0; j < VEC; ++j)
          o[j] = v[j] * 0.125f + bias[c0 + j] + rs[j];
      }
    }
  }
}

// ---------------- launch ----------------

extern "C" void kernel_launch(void* const* d_in, const int* in_sizes, int n_in,
                              void* d_out, int out_size, void* d_ws, size_t ws_size,
                              hipStream_t stream) {
  const float* x      = (const float*)d_in[0];
  const int*   ei     = (const int*)d_in[1];
  const float* lin1_w = (const float*)d_in[3];
  const float* lin1_b = (const float*)d_in[4];
  const float* wl1    = (const float*)d_in[5];
  const float* wr1    = (const float*)d_in[6];
  const float* att1   = (const float*)d_in[7];
  const float* b1     = (const float*)d_in[8];
  const float* wl2    = (const float*)d_in[9];
  const float* wr2    = (const float*)d_in[10];
  const float* att2   = (const float*)d_in[11];
  const float* b2     = (const float*)d_in[12];
  float* out = (float*)d_out;

  char* p = (char*)d_ws;
  auto alloc = [&](size_t bytes) {
    char* r = p;
    p += (bytes + 255) & ~size_t(255);
    return r;
  };
  int*   offs  = (int*)alloc((NNODE + 1) * 4);
  int*   deg   = (int*)alloc(NNODE * 4);
  int*   cur   = (int*)alloc(NNODE * 4);
  int*   bsum  = (int*)alloc(SCANB * 4);
  int*   csrc  = (int*)alloc((size_t)NTOT * 4);
  bf16*  xl    = (bf16*)alloc((size_t)NNODE * 512 * 2);
  bf16*  xr    = (bf16*)alloc((size_t)NNODE * 512 * 2);
  bf16*  h1    = (bf16*)alloc((size_t)NNODE * 64 * 2);
  bf16*  Bp1   = (bf16*)alloc((size_t)128 * 1024 * 2);
  bf16*  Bp2   = (bf16*)alloc((size_t)64 * 512 * 2);
  float* resid = (float*)alloc((size_t)NNODE * 32 * 4);

  (void)hipMemsetAsync(deg, 0, NNODE * 4, stream);
  (void)hipMemsetAsync(cur, 0, NNODE * 4, stream);

  // prep
  k_count<<<(NTOT + 255) / 256, 256, 0, stream>>>(ei, deg);
  k_scan1<<<SCANB, 256, 0, stream>>>(deg, offs, bsum);
  k_scan2<<<1, 256, 0, stream>>>(bsum, SCANB);
  k_scan3<<<SCANB, 256, 0, stream>>>(offs, bsum);
  k_fill<<<(NTOT + 255) / 256, 256, 0, stream>>>(ei, offs, cur, csrc);
  k_pack<128, 1024><<<64, 256, 0, stream>>>(wl1, wr1, Bp1);
  k_pack<64, 512><<<16, 256, 0, stream>>>(wl2, wr2, Bp2);
  k_residual<<<NNODE / 8, 256, 0, stream>>>(x, lin1_w, lin1_b, resid, NNODE);

  // layer 1 (A-cast fused; NF=16, y=1 -> A fetched ONCE)
  k_mfma<128, 1024, 16, true><<<dim3((NNODE + 31) / 32, 1), 256, 0, stream>>>(x, Bp1, xl, xr, NNODE);
  k_gat<512, 8, 2, true><<<NNODE, 128, 0, stream>>>(xl, xr, att1, csrc, offs, b1, nullptr, h1, nullptr);

  // layer 2 (NF=8 -> single y-block)
  k_mfma<64, 512, 8, false><<<dim3((NNODE + 31) / 32, 1), 256, 0, stream>>>(h1, Bp2, xl, xr, NNODE);
  k_gat<256, 4, 2, false><<<NNODE, 128, 0, stream>>>(xl, xr, att2, csrc, offs, b2, resid, nullptr, out);
}

// Round 14
// 269.370 us; speedup vs baseline: 1.2126x; 1.0110x over previous
//
#include <hip/hip_runtime.h>
#include <hip/hip_bf16.h>

#define NNODE 50000
#define NEDGE 400000
#define NTOT  450000   // NEDGE + NNODE self-loops
#define FDIM  128
#define HEADS 8
#define SCANB ((NNODE + 255) / 256)   // 196 blocks

typedef __bf16 bf16x8 __attribute__((ext_vector_type(8)));
typedef float  f32x4  __attribute__((ext_vector_type(4)));
typedef __hip_bfloat16 bf16;

// v_add with DPP cross-lane source: v + dpp(v). 0xB1=quad_perm[1,0,3,2](xor1),
// 0x4E=quad_perm[2,3,0,1](xor2), 0x141=row_half_mirror(xor4 after quad sums).
template<int CTRL>
static __device__ __forceinline__ float dpp_add(float v) {
  int x = __builtin_amdgcn_update_dpp(0, __float_as_int(v), CTRL, 0xf, 0xf, true);
  return v + __int_as_float(x);
}

// ---------------- CSR build ----------------

__global__ __launch_bounds__(256) void k_count(const int* __restrict__ ei, int* __restrict__ deg) {
  int t = blockIdx.x * 256 + threadIdx.x;
  if (t >= NTOT) return;
  int d = (t < NEDGE) ? ei[NEDGE + t] : (t - NEDGE);
  atomicAdd(&deg[d], 1);
}

__global__ __launch_bounds__(256) void k_scan1(const int* __restrict__ deg, int* __restrict__ offs,
                                               int* __restrict__ bsum) {
  __shared__ int buf[256];
  int i = blockIdx.x * 256 + threadIdx.x;
  int v = (i < NNODE) ? deg[i] : 0;
  buf[threadIdx.x] = v;
  __syncthreads();
  for (int off = 1; off < 256; off <<= 1) {
    int t = (threadIdx.x >= off) ? buf[threadIdx.x - off] : 0;
    __syncthreads();
    buf[threadIdx.x] += t;
    __syncthreads();
  }
  if (i < NNODE) offs[i + 1] = buf[threadIdx.x];
  if (threadIdx.x == 255) bsum[blockIdx.x] = buf[255];
  if (i == 0) offs[0] = 0;
}

__global__ __launch_bounds__(256) void k_scan2(int* __restrict__ bsum, int nb) {
  __shared__ int buf[256];
  int v = (threadIdx.x < nb) ? bsum[threadIdx.x] : 0;
  buf[threadIdx.x] = v;
  __syncthreads();
  for (int off = 1; off < 256; off <<= 1) {
    int t = (threadIdx.x >= off) ? buf[threadIdx.x - off] : 0;
    __syncthreads();
    buf[threadIdx.x] += t;
    __syncthreads();
  }
  if (threadIdx.x < nb) bsum[threadIdx.x] = buf[threadIdx.x] - v;
}

__global__ __launch_bounds__(256) void k_scan3(int* __restrict__ offs, const int* __restrict__ bsum) {
  int i = blockIdx.x * 256 + threadIdx.x;
  if (i < NNODE) offs[i + 1] += bsum[blockIdx.x];
}

__global__ __launch_bounds__(256) void k_fill(const int* __restrict__ ei, const int* __restrict__ offs,
                                              int* __restrict__ cur, int* __restrict__ csrc) {
  int t = blockIdx.x * 256 + threadIdx.x;
  if (t >= NTOT) return;
  int s, d;
  if (t < NEDGE) { s = ei[t]; d = ei[NEDGE + t]; }
  else { s = t - NEDGE; d = s; }
  int pos = offs[d] + atomicAdd(&cur[d], 1);
  csrc[pos] = s;
}

// ---------------- B pre-pack into MFMA fragment order ----------------

template<int K, int N>
__global__ __launch_bounds__(256) void k_pack(const float* __restrict__ Wl, const float* __restrict__ Wr,
                                              bf16* __restrict__ Bp) {
  constexpr int KS = K / 32;
  int t = blockIdx.x * 256 + threadIdx.x;
  if (t >= (N / 16) * KS * 64) return;
  int lane = t & 63;
  int ks = (t >> 6) % KS;
  int cb = t / (64 * KS);
  int col = cb * 16 + (lane & 15);
  int k0 = ks * 32 + (lane >> 4) * 8;
  const float* W = (col < N / 2) ? Wl : Wr;
  int c = (col < N / 2) ? col : col - N / 2;
  bf16* o = Bp + (size_t)t * 8;
#pragma unroll
  for (int j = 0; j < 8; ++j)
    o[j] = __float2bfloat16(W[(size_t)(k0 + j) * (N / 2) + c]);
}

// ---------------- MFMA dual GEMM (NF col-frags per wave; optional fused A-cast) ----------------

template<int K, int N, int NF, bool CVT>
__global__ __launch_bounds__(256) void k_mfma(const void* __restrict__ Aptr,
                                              const bf16* __restrict__ Bp,
                                              bf16* __restrict__ xl, bf16* __restrict__ xr,
                                              int n) {
  constexpr int KS = K / 32;
  const int lane = threadIdx.x & 63;
  const int wave = threadIdx.x >> 6;
  const int rb = blockIdx.x * 32;
  const int cb0 = blockIdx.y * (4 * NF) + wave * NF;
  const int r16 = lane & 15, kg = lane >> 4;

  bf16x8 a[2][KS];
#pragma unroll
  for (int mf = 0; mf < 2; ++mf) {
    int row = rb + 16 * mf + r16;
    if (row >= n) row = n - 1;
    if constexpr (CVT) {
      const float* pa = (const float*)Aptr + (size_t)row * K + kg * 8;
#pragma unroll
      for (int ks = 0; ks < KS; ++ks) {
        float4 f0 = *(const float4*)(pa + ks * 32);
        float4 f1 = *(const float4*)(pa + ks * 32 + 4);
        bf16x8 v;
        v[0] = __float2bfloat16(f0.x); v[1] = __float2bfloat16(f0.y);
        v[2] = __float2bfloat16(f0.z); v[3] = __float2bfloat16(f0.w);
        v[4] = __float2bfloat16(f1.x); v[5] = __float2bfloat16(f1.y);
        v[6] = __float2bfloat16(f1.z); v[7] = __float2bfloat16(f1.w);
        a[mf][ks] = v;
      }
    } else {
      const bf16* pa = (const bf16*)Aptr + (size_t)row * K + kg * 8;
#pragma unroll
      for (int ks = 0; ks < KS; ++ks)
        a[mf][ks] = *(const bf16x8*)(pa + ks * 32);
    }
  }

#pragma unroll
  for (int nf = 0; nf < NF; ++nf) {
    int cb = cb0 + nf;
    f32x4 acc0 = {0.f, 0.f, 0.f, 0.f}, acc1 = {0.f, 0.f, 0.f, 0.f};
    const bf16* pb = Bp + (size_t)cb * KS * 512 + lane * 8;
#pragma unroll
    for (int ks = 0; ks < KS; ++ks) {
      bf16x8 b = *(const bf16x8*)(pb + ks * 512);
      acc0 = __builtin_amdgcn_mfma_f32_16x16x32_bf16(a[0][ks], b, acc0, 0, 0, 0);
      acc1 = __builtin_amdgcn_mfma_f32_16x16x32_bf16(a[1][ks], b, acc1, 0, 0, 0);
    }
    int col = cb * 16 + r16;
    bf16* OUT; int c;
    if (col < N / 2) { OUT = xl; c = col; } else { OUT = xr; c = col - N / 2; }
#pragma unroll
    for (int reg = 0; reg < 4; ++reg) {
      int row0 = rb + kg * 4 + reg;
      if (row0 < n) OUT[(size_t)row0 * (N / 2) + c] = __float2bfloat16(acc0[reg]);
      int row1 = rb + 16 + kg * 4 + reg;
      if (row1 < n) OUT[(size_t)row1 * (N / 2) + c] = __float2bfloat16(acc1[reg]);
    }
  }
}

// ---------------- residual (fp32 vector; small) ----------------

__global__ __launch_bounds__(256) void k_residual(const float* __restrict__ X,
                                                  const float* __restrict__ W,
                                                  const float* __restrict__ b,
                                                  float* __restrict__ out, int n) {
  __shared__ float xs[8 * 128];
  int row0 = blockIdx.x * 8;
  for (int t = threadIdx.x; t < 8 * 128; t += 256) {
    int r = t >> 7;
    xs[t] = (row0 + r < n) ? X[(size_t)(row0 + r) * 128 + (t & 127)] : 0.f;
  }
  __syncthreads();
  int r = threadIdx.x >> 5, c = threadIdx.x & 31;
  float acc = 0.f;
  for (int k = 0; k < 128; ++k) acc += xs[r * 128 + k] * W[k * 32 + c];
  if (row0 + r < n) out[(size_t)(row0 + r) * 32 + c] = acc + b[c];
}

// ---------------- fused GATv2 layer (VERBATIM R8 proposal body: proven operating point) ----------------
// Block = W waves = ONE node; wave w handles edges beg+w, beg+w+W, ...
// Lane l: head l>>3, channels (l&7)*VEC + [0..VEC). Rows loaded as NW=VEC/2 u32 words.
// bf16->f32: lo = asfloat(w<<16), hi = asfloat(w & 0xffff0000)  (1 VALU/elem).
// lrelu(t)*a = (0.6a)t + (0.4a)|t|; att prescaled by log2(e) so wgt = v_exp_f32(s).
// Score reduce over 8 lanes via DPP adds. Max-free softmax (validated R6-R13).
// DO NOT EDIT BODY: register-allocation "improvements" (R9, R10, R11) regressed gat1
// 77 -> 94/104 us. W is a template param. R13: W=2 -> 72 us (fixed-cost halved).
// R14: W=1 — one prologue per node, cross-wave combine compiles away (w>0 dead,
// ww-loop empty). LDS arrays sized [W] (not W-1) so W=1 compiles; indexing unchanged.

template<int D, int VEC, int W, bool L1>
__global__ __launch_bounds__(64 * W, 2) void k_gat(const bf16* __restrict__ xl,
                                                   const bf16* __restrict__ xr,
                                                   const float* __restrict__ att,
                                                   const int* __restrict__ csrc,
                                                   const int* __restrict__ offs,
                                                   const float* __restrict__ bias,
                                                   const float* __restrict__ resid,
                                                   bf16* __restrict__ out1,
                                                   float* __restrict__ out2) {
  constexpr int CH = D / 8;
  constexpr int NW = VEC / 2;
  constexpr unsigned ROWB = D * 2;
  typedef unsigned int uivec __attribute__((ext_vector_type(NW)));
  __shared__ float sden[W][64];
  __shared__ float sacc[W][64][VEC + 1];
  const int w    = threadIdx.x >> 6;
  const int lane = threadIdx.x & 63;
  const int node = blockIdx.x;
  const int beg = offs[node], end = offs[node + 1], last = end - 1;

  const unsigned loff = (unsigned)(lane * VEC) * 2u;
  const char* xlp = (const char*)xl + loff;

  // per-lane constants: prescaled att halves + xr slice
  float a6[VEC], a4[VEC], xrv[VEC];
  {
    const float* pa = att + lane * VEC;
    const unsigned int* rw = (const unsigned int*)((const char*)xr + (size_t)node * ROWB + loff);
#pragma unroll
    for (int p = 0; p < NW; ++p) {
      unsigned int rv = rw[p];
      xrv[2 * p]     = __uint_as_float(rv << 16);
      xrv[2 * p + 1] = __uint_as_float(rv & 0xffff0000u);
    }
#pragma unroll
    for (int j = 0; j < VEC; ++j) {
      float a = pa[j] * 1.44269504f;   // fold exp->exp2
      a6[j] = 0.6f * a;
      a4[j] = 0.4f * a;
    }
  }

  float den = 0.f;
  float acc[VEC];
#pragma unroll
  for (int j = 0; j < VEC; ++j) acc[j] = 0.f;

  // per-edge score partial (pre-reduce): converts row words, returns s; av filled
  auto escore = [&](uivec Wd, float* av) -> float {
    float s0 = 0.f, s1 = 0.f;
#pragma unroll
    for (int p = 0; p < NW; ++p) {
      av[2 * p]     = __uint_as_float(Wd[p] << 16);
      av[2 * p + 1] = __uint_as_float(Wd[p] & 0xffff0000u);
    }
#pragma unroll
    for (int j = 0; j < VEC; ++j) {
      float t = av[j] + xrv[j];
      s0 = fmaf(a6[j], t, s0);
      s1 = fmaf(a4[j], fabsf(t), s1);
    }
    return s0 + s1;
  };

  int i = beg + w;
  if (i < end) {
    uivec A0 = *(const uivec*)(xlp + (unsigned)csrc[i] * ROWB);
    int i1 = (i + W < end) ? i + W : last;
    uivec A1 = *(const uivec*)(xlp + (unsigned)csrc[i1] * ROWB);
    for (; i + W < end; i += 2 * W) {
      int i2 = (i + 2 * W < end) ? i + 2 * W : last;
      int i3 = (i + 3 * W < end) ? i + 3 * W : last;
      uivec B0 = *(const uivec*)(xlp + (unsigned)csrc[i2] * ROWB);
      uivec B1 = *(const uivec*)(xlp + (unsigned)csrc[i3] * ROWB);

      float av0[VEC], av1[VEC];
      float s0 = escore(A0, av0);
      float s1 = escore(A1, av1);
      s0 = dpp_add<0xB1>(s0);   s1 = dpp_add<0xB1>(s1);    // xor1
      s0 = dpp_add<0x4E>(s0);   s1 = dpp_add<0x4E>(s1);    // xor2
      s0 = dpp_add<0x141>(s0);  s1 = dpp_add<0x141>(s1);   // xor4 (half-mirror)
      float w0, w1;
      asm("v_exp_f32 %0, %1" : "=v"(w0) : "v"(s0));   // 2^s = exp(sc)
      asm("v_exp_f32 %0, %1" : "=v"(w1) : "v"(s1));
      den += w0;
      den += w1;
#pragma unroll
      for (int j = 0; j < VEC; ++j) {
        acc[j] = fmaf(w0, av0[j], acc[j]);
        acc[j] = fmaf(w1, av1[j], acc[j]);
      }
      A0 = B0; A1 = B1;
    }
    if (i < end) {   // tail single edge
      float av0[VEC];
      float s0 = escore(A0, av0);
      s0 = dpp_add<0xB1>(s0);
      s0 = dpp_add<0x4E>(s0);
      s0 = dpp_add<0x141>(s0);
      float w0;
      asm("v_exp_f32 %0, %1" : "=v"(w0) : "v"(s0));
      den += w0;
#pragma unroll
      for (int j = 0; j < VEC; ++j) acc[j] = fmaf(w0, av0[j], acc[j]);
    }
  }

  if (w > 0) {
    sden[w - 1][lane] = den;
#pragma unroll
    for (int j = 0; j < VEC; ++j) sacc[w - 1][lane][j] = acc[j];
  }
  __syncthreads();
  if (w == 0) {
#pragma unroll
    for (int ww = 0; ww < W - 1; ++ww) {
      den += sden[ww][lane];
#pragma unroll
      for (int j = 0; j < VEC; ++j) acc[j] += sacc[ww][lane][j];
    }
    const float inv = 1.f / den;
    float v[VEC];
#pragma unroll
    for (int j = 0; j < VEC; ++j) {
      float t = acc[j] * inv;
      t += __shfl_xor(t, 8);
      t += __shfl_xor(t, 16);
      t += __shfl_xor(t, 32);
      v[j] = t;
    }
    if (lane < 8) {
      int c0 = lane * VEC;
      if constexpr (L1) {
        bf16* o = out1 + (size_t)node * CH + c0;
#pragma unroll
        for (int j = 0; j < VEC; ++j) {
          float t = v[j] * 0.125f + bias[c0 + j];
          o[j] = __float2bfloat16(fmaxf(t, 0.f));
        }
      } else {
        float* o = out2 + (size_t)node * CH + c0;
        const float* rs = resid + (size_t)node * CH + c0;
#pragma unroll
        for (int j = 0; j < VEC; ++j)
          o[j] = v[j] * 0.125f + bias[c0 + j] + rs[j];
      }
    }
  }
}

// ---------------- launch ----------------

extern "C" void kernel_launch(void* const* d_in, const int* in_sizes, int n_in,
                              void* d_out, int out_size, void* d_ws, size_t ws_size,
                              hipStream_t stream) {
  const float* x      = (const float*)d_in[0];
  const int*   ei     = (const int*)d_in[1];
  const float* lin1_w = (const float*)d_in[3];
  const float* lin1_b = (const float*)d_in[4];
  const float* wl1    = (const float*)d_in[5];
  const float* wr1    = (const float*)d_in[6];
  const float* att1   = (const float*)d_in[7];
  const float* b1     = (const float*)d_in[8];
  const float* wl2    = (const float*)d_in[9];
  const float* wr2    = (const float*)d_in[10];
  const float* att2   = (const float*)d_in[11];
  const float* b2     = (const float*)d_in[12];
  float* out = (float*)d_out;

  char* p = (char*)d_ws;
  auto alloc = [&](size_t bytes) {
    char* r = p;
    p += (bytes + 255) & ~size_t(255);
    return r;
  };
  int*   offs  = (int*)alloc((NNODE + 1) * 4);
  int*   deg   = (int*)alloc(NNODE * 4);
  int*   cur   = (int*)alloc(NNODE * 4);
  int*   bsum  = (int*)alloc(SCANB * 4);
  int*   csrc  = (int*)alloc((size_t)NTOT * 4);
  bf16*  xl    = (bf16*)alloc((size_t)NNODE * 512 * 2);
  bf16*  xr    = (bf16*)alloc((size_t)NNODE * 512 * 2);
  bf16*  h1    = (bf16*)alloc((size_t)NNODE * 64 * 2);
  bf16*  Bp1   = (bf16*)alloc((size_t)128 * 1024 * 2);
  bf16*  Bp2   = (bf16*)alloc((size_t)64 * 512 * 2);
  float* resid = (float*)alloc((size_t)NNODE * 32 * 4);

  (void)hipMemsetAsync(deg, 0, NNODE * 4, stream);
  (void)hipMemsetAsync(cur, 0, NNODE * 4, stream);

  // prep
  k_count<<<(NTOT + 255) / 256, 256, 0, stream>>>(ei, deg);
  k_scan1<<<SCANB, 256, 0, stream>>>(deg, offs, bsum);
  k_scan2<<<1, 256, 0, stream>>>(bsum, SCANB);
  k_scan3<<<SCANB, 256, 0, stream>>>(offs, bsum);
  k_fill<<<(NTOT + 255) / 256, 256, 0, stream>>>(ei, offs, cur, csrc);
  k_pack<128, 1024><<<64, 256, 0, stream>>>(wl1, wr1, Bp1);
  k_pack<64, 512><<<16, 256, 0, stream>>>(wl2, wr2, Bp2);
  k_residual<<<NNODE / 8, 256, 0, stream>>>(x, lin1_w, lin1_b, resid, NNODE);

  // layer 1 (A-cast fused; NF=16, y=1 -> A fetched ONCE)
  k_mfma<128, 1024, 16, true><<<dim3((NNODE + 31) / 32, 1), 256, 0, stream>>>(x, Bp1, xl, xr, NNODE);
  k_gat<512, 8, 1, true><<<NNODE, 64, 0, stream>>>(xl, xr, att1, csrc, offs, b1, nullptr, h1, nullptr);

  // layer 2 (NF=8 -> single y-block)
  k_mfma<64, 512, 8, false><<<dim3((NNODE + 31) / 32, 1), 256, 0, stream>>>(h1, Bp2, xl, xr, NNODE);
  k_gat<256, 4, 1, false><<<NNODE, 64, 0, stream>>>(xl, xr, att2, csrc, offs, b2, resid, nullptr, out);
}

// Round 15
// 265.900 us; speedup vs baseline: 1.2284x; 1.0131x over previous
//
#include <hip/hip_runtime.h>
#include <hip/hip_bf16.h>

#define NNODE 50000
#define NEDGE 400000
#define NTOT  450000   // NEDGE + NNODE self-loops
#define FDIM  128
#define HEADS 8
#define SCANB ((NNODE + 255) / 256)   // 196 blocks

typedef __bf16 bf16x8 __attribute__((ext_vector_type(8)));
typedef float  f32x4  __attribute__((ext_vector_type(4)));
typedef __hip_bfloat16 bf16;

// v_add with DPP cross-lane source: v + dpp(v). 0xB1=quad_perm[1,0,3,2](xor1),
// 0x4E=quad_perm[2,3,0,1](xor2), 0x141=row_half_mirror(xor4 after quad sums).
template<int CTRL>
static __device__ __forceinline__ float dpp_add(float v) {
  int x = __builtin_amdgcn_update_dpp(0, __float_as_int(v), CTRL, 0xf, 0xf, true);
  return v + __int_as_float(x);
}

// ---------------- CSR build ----------------

__global__ __launch_bounds__(256) void k_count(const int* __restrict__ ei, int* __restrict__ deg) {
  int t = blockIdx.x * 256 + threadIdx.x;
  if (t >= NTOT) return;
  int d = (t < NEDGE) ? ei[NEDGE + t] : (t - NEDGE);
  atomicAdd(&deg[d], 1);
}

__global__ __launch_bounds__(256) void k_scan1(const int* __restrict__ deg, int* __restrict__ offs,
                                               int* __restrict__ bsum) {
  __shared__ int buf[256];
  int i = blockIdx.x * 256 + threadIdx.x;
  int v = (i < NNODE) ? deg[i] : 0;
  buf[threadIdx.x] = v;
  __syncthreads();
  for (int off = 1; off < 256; off <<= 1) {
    int t = (threadIdx.x >= off) ? buf[threadIdx.x - off] : 0;
    __syncthreads();
    buf[threadIdx.x] += t;
    __syncthreads();
  }
  if (i < NNODE) offs[i + 1] = buf[threadIdx.x];
  if (threadIdx.x == 255) bsum[blockIdx.x] = buf[255];
  if (i == 0) offs[0] = 0;
}

__global__ __launch_bounds__(256) void k_scan2(int* __restrict__ bsum, int nb) {
  __shared__ int buf[256];
  int v = (threadIdx.x < nb) ? bsum[threadIdx.x] : 0;
  buf[threadIdx.x] = v;
  __syncthreads();
  for (int off = 1; off < 256; off <<= 1) {
    int t = (threadIdx.x >= off) ? buf[threadIdx.x - off] : 0;
    __syncthreads();
    buf[threadIdx.x] += t;
    __syncthreads();
  }
  if (threadIdx.x < nb) bsum[threadIdx.x] = buf[threadIdx.x] - v;
}

__global__ __launch_bounds__(256) void k_scan3(int* __restrict__ offs, const int* __restrict__ bsum) {
  int i = blockIdx.x * 256 + threadIdx.x;
  if (i < NNODE) offs[i + 1] += bsum[blockIdx.x];
}

__global__ __launch_bounds__(256) void k_fill(const int* __restrict__ ei, const int* __restrict__ offs,
                                              int* __restrict__ cur, int* __restrict__ csrc) {
  int t = blockIdx.x * 256 + threadIdx.x;
  if (t >= NTOT) return;
  int s, d;
  if (t < NEDGE) { s = ei[t]; d = ei[NEDGE + t]; }
  else { s = t - NEDGE; d = s; }
  int pos = offs[d] + atomicAdd(&cur[d], 1);
  csrc[pos] = s;
}

// ---------------- B pre-pack into MFMA fragment order ----------------

template<int K, int N>
__global__ __launch_bounds__(256) void k_pack(const float* __restrict__ Wl, const float* __restrict__ Wr,
                                              bf16* __restrict__ Bp) {
  constexpr int KS = K / 32;
  int t = blockIdx.x * 256 + threadIdx.x;
  if (t >= (N / 16) * KS * 64) return;
  int lane = t & 63;
  int ks = (t >> 6) % KS;
  int cb = t / (64 * KS);
  int col = cb * 16 + (lane & 15);
  int k0 = ks * 32 + (lane >> 4) * 8;
  const float* W = (col < N / 2) ? Wl : Wr;
  int c = (col < N / 2) ? col : col - N / 2;
  bf16* o = Bp + (size_t)t * 8;
#pragma unroll
  for (int j = 0; j < 8; ++j)
    o[j] = __float2bfloat16(W[(size_t)(k0 + j) * (N / 2) + c]);
}

// ---------------- MFMA dual GEMM (NF col-frags per wave; optional fused A-cast) ----------------

template<int K, int N, int NF, bool CVT>
__global__ __launch_bounds__(256) void k_mfma(const void* __restrict__ Aptr,
                                              const bf16* __restrict__ Bp,
                                              bf16* __restrict__ xl, bf16* __restrict__ xr,
                                              int n) {
  constexpr int KS = K / 32;
  const int lane = threadIdx.x & 63;
  const int wave = threadIdx.x >> 6;
  const int rb = blockIdx.x * 32;
  const int cb0 = blockIdx.y * (4 * NF) + wave * NF;
  const int r16 = lane & 15, kg = lane >> 4;

  bf16x8 a[2][KS];
#pragma unroll
  for (int mf = 0; mf < 2; ++mf) {
    int row = rb + 16 * mf + r16;
    if (row >= n) row = n - 1;
    if constexpr (CVT) {
      const float* pa = (const float*)Aptr + (size_t)row * K + kg * 8;
#pragma unroll
      for (int ks = 0; ks < KS; ++ks) {
        float4 f0 = *(const float4*)(pa + ks * 32);
        float4 f1 = *(const float4*)(pa + ks * 32 + 4);
        bf16x8 v;
        v[0] = __float2bfloat16(f0.x); v[1] = __float2bfloat16(f0.y);
        v[2] = __float2bfloat16(f0.z); v[3] = __float2bfloat16(f0.w);
        v[4] = __float2bfloat16(f1.x); v[5] = __float2bfloat16(f1.y);
        v[6] = __float2bfloat16(f1.z); v[7] = __float2bfloat16(f1.w);
        a[mf][ks] = v;
      }
    } else {
      const bf16* pa = (const bf16*)Aptr + (size_t)row * K + kg * 8;
#pragma unroll
      for (int ks = 0; ks < KS; ++ks)
        a[mf][ks] = *(const bf16x8*)(pa + ks * 32);
    }
  }

#pragma unroll
  for (int nf = 0; nf < NF; ++nf) {
    int cb = cb0 + nf;
    f32x4 acc0 = {0.f, 0.f, 0.f, 0.f}, acc1 = {0.f, 0.f, 0.f, 0.f};
    const bf16* pb = Bp + (size_t)cb * KS * 512 + lane * 8;
#pragma unroll
    for (int ks = 0; ks < KS; ++ks) {
      bf16x8 b = *(const bf16x8*)(pb + ks * 512);
      acc0 = __builtin_amdgcn_mfma_f32_16x16x32_bf16(a[0][ks], b, acc0, 0, 0, 0);
      acc1 = __builtin_amdgcn_mfma_f32_16x16x32_bf16(a[1][ks], b, acc1, 0, 0, 0);
    }
    int col = cb * 16 + r16;
    bf16* OUT; int c;
    if (col < N / 2) { OUT = xl; c = col; } else { OUT = xr; c = col - N / 2; }
#pragma unroll
    for (int reg = 0; reg < 4; ++reg) {
      int row0 = rb + kg * 4 + reg;
      if (row0 < n) OUT[(size_t)row0 * (N / 2) + c] = __float2bfloat16(acc0[reg]);
      int row1 = rb + 16 + kg * 4 + reg;
      if (row1 < n) OUT[(size_t)row1 * (N / 2) + c] = __float2bfloat16(acc1[reg]);
    }
  }
}

// ---------------- residual (fp32 vector; small) ----------------

__global__ __launch_bounds__(256) void k_residual(const float* __restrict__ X,
                                                  const float* __restrict__ W,
                                                  const float* __restrict__ b,
                                                  float* __restrict__ out, int n) {
  __shared__ float xs[8 * 128];
  int row0 = blockIdx.x * 8;
  for (int t = threadIdx.x; t < 8 * 128; t += 256) {
    int r = t >> 7;
    xs[t] = (row0 + r < n) ? X[(size_t)(row0 + r) * 128 + (t & 127)] : 0.f;
  }
  __syncthreads();
  int r = threadIdx.x >> 5, c = threadIdx.x & 31;
  float acc = 0.f;
  for (int k = 0; k < 128; ++k) acc += xs[r * 128 + k] * W[k * 32 + c];
  if (row0 + r < n) out[(size_t)(row0 + r) * 32 + c] = acc + b[c];
}

// ---------------- fused GATv2 layer (VERBATIM R8 proposal body: proven operating point) ----------------
// Block = W waves = ONE node; wave w handles edges beg+w, beg+w+W, ...
// Lane l: head l>>3, channels (l&7)*VEC + [0..VEC). Rows loaded as NW=VEC/2 u32 words.
// bf16->f32: lo = asfloat(w<<16), hi = asfloat(w & 0xffff0000)  (1 VALU/elem).
// lrelu(t)*a = (0.6a)t + (0.4a)|t|; att prescaled by log2(e) so wgt = v_exp_f32(s).
// Score reduce over 8 lanes via DPP adds. Max-free softmax (validated R6-R14).
// DO NOT EDIT BODY: register-allocation "improvements" (R9, R10, R11) regressed gat1
// 77 -> 94/104 us. W is a template param, tuned per layer (R13/R14 measurements):
//   L1 (1KB rows):  W=2 -> 72.2us (cross-wave latency overlap wins)
//   L2 (512B rows): W=1 -> best  (prologue amortization wins, combine compiles away)

template<int D, int VEC, int W, bool L1>
__global__ __launch_bounds__(64 * W, 2) void k_gat(const bf16* __restrict__ xl,
                                                   const bf16* __restrict__ xr,
                                                   const float* __restrict__ att,
                                                   const int* __restrict__ csrc,
                                                   const int* __restrict__ offs,
                                                   const float* __restrict__ bias,
                                                   const float* __restrict__ resid,
                                                   bf16* __restrict__ out1,
                                                   float* __restrict__ out2) {
  constexpr int CH = D / 8;
  constexpr int NW = VEC / 2;
  constexpr unsigned ROWB = D * 2;
  typedef unsigned int uivec __attribute__((ext_vector_type(NW)));
  __shared__ float sden[W][64];
  __shared__ float sacc[W][64][VEC + 1];
  const int w    = threadIdx.x >> 6;
  const int lane = threadIdx.x & 63;
  const int node = blockIdx.x;
  const int beg = offs[node], end = offs[node + 1], last = end - 1;

  const unsigned loff = (unsigned)(lane * VEC) * 2u;
  const char* xlp = (const char*)xl + loff;

  // per-lane constants: prescaled att halves + xr slice
  float a6[VEC], a4[VEC], xrv[VEC];
  {
    const float* pa = att + lane * VEC;
    const unsigned int* rw = (const unsigned int*)((const char*)xr + (size_t)node * ROWB + loff);
#pragma unroll
    for (int p = 0; p < NW; ++p) {
      unsigned int rv = rw[p];
      xrv[2 * p]     = __uint_as_float(rv << 16);
      xrv[2 * p + 1] = __uint_as_float(rv & 0xffff0000u);
    }
#pragma unroll
    for (int j = 0; j < VEC; ++j) {
      float a = pa[j] * 1.44269504f;   // fold exp->exp2
      a6[j] = 0.6f * a;
      a4[j] = 0.4f * a;
    }
  }

  float den = 0.f;
  float acc[VEC];
#pragma unroll
  for (int j = 0; j < VEC; ++j) acc[j] = 0.f;

  // per-edge score partial (pre-reduce): converts row words, returns s; av filled
  auto escore = [&](uivec Wd, float* av) -> float {
    float s0 = 0.f, s1 = 0.f;
#pragma unroll
    for (int p = 0; p < NW; ++p) {
      av[2 * p]     = __uint_as_float(Wd[p] << 16);
      av[2 * p + 1] = __uint_as_float(Wd[p] & 0xffff0000u);
    }
#pragma unroll
    for (int j = 0; j < VEC; ++j) {
      float t = av[j] + xrv[j];
      s0 = fmaf(a6[j], t, s0);
      s1 = fmaf(a4[j], fabsf(t), s1);
    }
    return s0 + s1;
  };

  int i = beg + w;
  if (i < end) {
    uivec A0 = *(const uivec*)(xlp + (unsigned)csrc[i] * ROWB);
    int i1 = (i + W < end) ? i + W : last;
    uivec A1 = *(const uivec*)(xlp + (unsigned)csrc[i1] * ROWB);
    for (; i + W < end; i += 2 * W) {
      int i2 = (i + 2 * W < end) ? i + 2 * W : last;
      int i3 = (i + 3 * W < end) ? i + 3 * W : last;
      uivec B0 = *(const uivec*)(xlp + (unsigned)csrc[i2] * ROWB);
      uivec B1 = *(const uivec*)(xlp + (unsigned)csrc[i3] * ROWB);

      float av0[VEC], av1[VEC];
      float s0 = escore(A0, av0);
      float s1 = escore(A1, av1);
      s0 = dpp_add<0xB1>(s0);   s1 = dpp_add<0xB1>(s1);    // xor1
      s0 = dpp_add<0x4E>(s0);   s1 = dpp_add<0x4E>(s1);    // xor2
      s0 = dpp_add<0x141>(s0);  s1 = dpp_add<0x141>(s1);   // xor4 (half-mirror)
      float w0, w1;
      asm("v_exp_f32 %0, %1" : "=v"(w0) : "v"(s0));   // 2^s = exp(sc)
      asm("v_exp_f32 %0, %1" : "=v"(w1) : "v"(s1));
      den += w0;
      den += w1;
#pragma unroll
      for (int j = 0; j < VEC; ++j) {
        acc[j] = fmaf(w0, av0[j], acc[j]);
        acc[j] = fmaf(w1, av1[j], acc[j]);
      }
      A0 = B0; A1 = B1;
    }
    if (i < end) {   // tail single edge
      float av0[VEC];
      float s0 = escore(A0, av0);
      s0 = dpp_add<0xB1>(s0);
      s0 = dpp_add<0x4E>(s0);
      s0 = dpp_add<0x141>(s0);
      float w0;
      asm("v_exp_f32 %0, %1" : "=v"(w0) : "v"(s0));
      den += w0;
#pragma unroll
      for (int j = 0; j < VEC; ++j) acc[j] = fmaf(w0, av0[j], acc[j]);
    }
  }

  if (w > 0) {
    sden[w - 1][lane] = den;
#pragma unroll
    for (int j = 0; j < VEC; ++j) sacc[w - 1][lane][j] = acc[j];
  }
  __syncthreads();
  if (w == 0) {
#pragma unroll
    for (int ww = 0; ww < W - 1; ++ww) {
      den += sden[ww][lane];
#pragma unroll
      for (int j = 0; j < VEC; ++j) acc[j] += sacc[ww][lane][j];
    }
    const float inv = 1.f / den;
    float v[VEC];
#pragma unroll
    for (int j = 0; j < VEC; ++j) {
      float t = acc[j] * inv;
      t += __shfl_xor(t, 8);
      t += __shfl_xor(t, 16);
      t += __shfl_xor(t, 32);
      v[j] = t;
    }
    if (lane < 8) {
      int c0 = lane * VEC;
      if constexpr (L1) {
        bf16* o = out1 + (size_t)node * CH + c0;
#pragma unroll
        for (int j = 0; j < VEC; ++j) {
          float t = v[j] * 0.125f + bias[c0 + j];
          o[j] = __float2bfloat16(fmaxf(t, 0.f));
        }
      } else {
        float* o = out2 + (size_t)node * CH + c0;
        const float* rs = resid + (size_t)node * CH + c0;
#pragma unroll
        for (int j = 0; j < VEC; ++j)
          o[j] = v[j] * 0.125f + bias[c0 + j] + rs[j];
      }
    }
  }
}

// ---------------- launch ----------------

extern "C" void kernel_launch(void* const* d_in, const int* in_sizes, int n_in,
                              void* d_out, int out_size, void* d_ws, size_t ws_size,
                              hipStream_t stream) {
  const float* x      = (const float*)d_in[0];
  const int*   ei     = (const int*)d_in[1];
  const float* lin1_w = (const float*)d_in[3];
  const float* lin1_b = (const float*)d_in[4];
  const float* wl1    = (const float*)d_in[5];
  const float* wr1    = (const float*)d_in[6];
  const float* att1   = (const float*)d_in[7];
  const float* b1     = (const float*)d_in[8];
  const float* wl2    = (const float*)d_in[9];
  const float* wr2    = (const float*)d_in[10];
  const float* att2   = (const float*)d_in[11];
  const float* b2     = (const float*)d_in[12];
  float* out = (float*)d_out;

  char* p = (char*)d_ws;
  auto alloc = [&](size_t bytes) {
    char* r = p;
    p += (bytes + 255) & ~size_t(255);
    return r;
  };
  int*   offs  = (int*)alloc((NNODE + 1) * 4);
  int*   deg   = (int*)alloc(NNODE * 4);
  int*   cur   = (int*)alloc(NNODE * 4);
  int*   bsum  = (int*)alloc(SCANB * 4);
  int*   csrc  = (int*)alloc((size_t)NTOT * 4);
  bf16*  xl    = (bf16*)alloc((size_t)NNODE * 512 * 2);
  bf16*  xr    = (bf16*)alloc((size_t)NNODE * 512 * 2);
  bf16*  h1    = (bf16*)alloc((size_t)NNODE * 64 * 2);
  bf16*  Bp1   = (bf16*)alloc((size_t)128 * 1024 * 2);
  bf16*  Bp2   = (bf16*)alloc((size_t)64 * 512 * 2);
  float* resid = (float*)alloc((size_t)NNODE * 32 * 4);

  (void)hipMemsetAsync(deg, 0, NNODE * 4, stream);
  (void)hipMemsetAsync(cur, 0, NNODE * 4, stream);

  // prep
  k_count<<<(NTOT + 255) / 256, 256, 0, stream>>>(ei, deg);
  k_scan1<<<SCANB, 256, 0, stream>>>(deg, offs, bsum);
  k_scan2<<<1, 256, 0, stream>>>(bsum, SCANB);
  k_scan3<<<SCANB, 256, 0, stream>>>(offs, bsum);
  k_fill<<<(NTOT + 255) / 256, 256, 0, stream>>>(ei, offs, cur, csrc);
  k_pack<128, 1024><<<64, 256, 0, stream>>>(wl1, wr1, Bp1);
  k_pack<64, 512><<<16, 256, 0, stream>>>(wl2, wr2, Bp2);
  k_residual<<<NNODE / 8, 256, 0, stream>>>(x, lin1_w, lin1_b, resid, NNODE);

  // layer 1 (A-cast fused; NF=16, y=1 -> A fetched ONCE; gat W=2: 1KB rows)
  k_mfma<128, 1024, 16, true><<<dim3((NNODE + 31) / 32, 1), 256, 0, stream>>>(x, Bp1, xl, xr, NNODE);
  k_gat<512, 8, 2, true><<<NNODE, 128, 0, stream>>>(xl, xr, att1, csrc, offs, b1, nullptr, h1, nullptr);

  // layer 2 (NF=8 -> single y-block; gat W=1: 512B rows)
  k_mfma<64, 512, 8, false><<<dim3((NNODE + 31) / 32, 1), 256, 0, stream>>>(h1, Bp2, xl, xr, NNODE);
  k_gat<256, 4, 1, false><<<NNODE, 64, 0, stream>>>(xl, xr, att2, csrc, offs, b2, resid, nullptr, out);
}